// Round 1
// baseline (2810.000 us; speedup 1.0000x reference)
//
#include <hip/hip_runtime.h>
#include <stdint.h>

#define N 8192

// ---------------- Kernel 1: bitonic sort of composite keys ----------------
// key = (~monotone(score) << 32) | index  -> ascending sort == stable
// argsort of -scores (score desc, index asc on ties).
__global__ __launch_bounds__(1024) void k_sort(const float* __restrict__ scores,
                                               uint32_t* __restrict__ order) {
    __shared__ uint64_t keys[N];
    int t = threadIdx.x;
    for (int e = 0; e < 8; ++e) {
        int i = t + e * 1024;
        uint32_t sb = __float_as_uint(scores[i]);
        sb = (sb & 0x80000000u) ? ~sb : (sb | 0x80000000u);  // ascending-monotone
        keys[i] = ((uint64_t)(~sb) << 32) | (uint32_t)i;     // descending score, asc idx
    }
    __syncthreads();
    for (int k = 2; k <= N; k <<= 1) {
        for (int j = k >> 1; j > 0; j >>= 1) {
            for (int e = 0; e < 8; ++e) {
                int i = t + e * 1024;
                int ixj = i ^ j;
                if (ixj > i) {
                    uint64_t a = keys[i], b = keys[ixj];
                    bool up = ((i & k) == 0);
                    if ((a > b) == up) { keys[i] = b; keys[ixj] = a; }
                }
            }
            __syncthreads();
        }
    }
    for (int e = 0; e < 8; ++e) {
        int i = t + e * 1024;
        order[i] = (uint32_t)keys[i];
    }
}

// ---------------- Kernel 2: gather sorted boxes/scores ----------------
__global__ void k_gather(const float4* __restrict__ boxes,
                         const float* __restrict__ scores,
                         const uint32_t* __restrict__ order,
                         float4* __restrict__ bs, float* __restrict__ ss) {
    int i = blockIdx.x * blockDim.x + threadIdx.x;
    uint32_t j = order[i];
    bs[i] = boxes[j];
    ss[i] = scores[j];
}

// ---------------- Kernel 3: suppression bitmask ----------------
// Block handles 64 rows x 2048 cols. Each wave's 64 lanes = 64 consecutive
// columns; __ballot packs one uint64 word per row. mask[row*128 + word].
__global__ __launch_bounds__(256) void k_mask(const float4* __restrict__ bs,
                                              uint64_t* __restrict__ mask) {
    __shared__ float4 rb[64];
    __shared__ float  ra[64];
    int R = blockIdx.x & 127;   // row block
    int C = blockIdx.x >> 7;    // col quarter (0..3)
    int t = threadIdx.x;
    int lane = t & 63;
    int wv = t >> 6;
    if (t < 64) {
        float4 b = bs[R * 64 + t];
        rb[t] = b;
        ra[t] = ((b.z - b.x) + 1.0f) * ((b.w - b.y) + 1.0f);
    }
    __syncthreads();
    for (int c = 0; c < 8; ++c) {
        int word = C * 32 + wv * 8 + c;
        int col = word * 64 + lane;
        float4 cb = bs[col];
        float ca = ((cb.z - cb.x) + 1.0f) * ((cb.w - cb.y) + 1.0f);
        for (int r = 0; r < 64; ++r) {
            int row = R * 64 + r;
            float4 rbv = rb[r];
            float ix1 = fmaxf(rbv.x, cb.x);
            float iy1 = fmaxf(rbv.y, cb.y);
            float ix2 = fminf(rbv.z, cb.z);
            float iy2 = fminf(rbv.w, cb.w);
            float iw = fmaxf((ix2 - ix1) + 1.0f, 0.0f);
            float ih = fmaxf((iy2 - iy1) + 1.0f, 0.0f);
            float inter = iw * ih;
            float uni = (ra[r] + ca) - inter;   // matches ref: (a_i + a_j) - inter
            float iou = inter / uni;            // IEEE div, matches numpy ref
            bool pred = (iou > 0.5f) && (col > row);
            uint64_t bal = __ballot(pred);
            if (lane == 0) mask[(size_t)row * 128 + word] = bal;
        }
    }
}

// ---------------- Kernel 4: sequential greedy scan (one wave) ----------------
// Lane l holds remv words l and l+64 in registers. Final keep = ~remv, since
// row j only sets bits for columns > j (so a row's bit is final by its turn).
__global__ __launch_bounds__(64) void k_scan(const uint64_t* __restrict__ mask,
                                             uint64_t* __restrict__ remv) {
    int lane = threadIdx.x;
    uint64_t rlo = 0, rhi = 0;
    uint64_t pl[8], ph[8];
#pragma unroll
    for (int u = 0; u < 8; ++u) {
        pl[u] = mask[(size_t)u * 128 + lane];
        ph[u] = mask[(size_t)u * 128 + 64 + lane];
    }
    for (int base = 0; base < N; base += 8) {
#pragma unroll
        for (int u = 0; u < 8; ++u) {
            int i = base + u;
            int w = i >> 6, b = i & 63;
            uint64_t v = (w >= 64) ? rhi : rlo;
            uint32_t h = (b >= 32) ? (uint32_t)(v >> 32) : (uint32_t)v;
            uint32_t x = (uint32_t)__shfl((int)h, w & 63, 64);
            uint64_t ml = pl[u], mh = ph[u];
            int nx = i + 8;
            if (nx < N) {
                pl[u] = mask[(size_t)nx * 128 + lane];
                ph[u] = mask[(size_t)nx * 128 + 64 + lane];
            }
            if (!((x >> (b & 31)) & 1u)) { rlo |= ml; rhi |= mh; }
        }
    }
    remv[lane] = rlo;
    remv[64 + lane] = rhi;
}

// ---------------- Kernel 5: masked outputs ----------------
__global__ void k_out(const float4* __restrict__ bs, const float* __restrict__ ss,
                      const uint64_t* __restrict__ remv, float* __restrict__ out) {
    int i = blockIdx.x * blockDim.x + threadIdx.x;
    uint64_t wv = remv[i >> 6];
    float m = ((wv >> (i & 63)) & 1ull) ? 0.0f : 1.0f;
    float4 b = bs[i];
    float4 ob;
    ob.x = b.x * m; ob.y = b.y * m; ob.z = b.z * m; ob.w = b.w * m;
    ((float4*)out)[i] = ob;
    out[4 * N + i] = ss[i] * m;
    out[5 * N + i] = m;
}

extern "C" void kernel_launch(void* const* d_in, const int* in_sizes, int n_in,
                              void* d_out, int out_size, void* d_ws, size_t ws_size,
                              hipStream_t stream) {
    const float* boxes  = (const float*)d_in[0];   // 8192 x 4 f32
    const float* scores = (const float*)d_in[1];   // 8192 f32

    char* ws = (char*)d_ws;
    float4*   bs    = (float4*)(ws + 0);        // 131072 B
    float*    ss    = (float*)(ws + 131072);    //  32768 B
    uint32_t* order = (uint32_t*)(ws + 163840); //  32768 B
    uint64_t* remv  = (uint64_t*)(ws + 196608); //   1024 B
    uint64_t* mask  = (uint64_t*)(ws + 262144); // 8388608 B (8192 rows x 128 words)

    k_sort  <<<1, 1024, 0, stream>>>(scores, order);
    k_gather<<<N / 256, 256, 0, stream>>>((const float4*)boxes, scores, order, bs, ss);
    k_mask  <<<512, 256, 0, stream>>>(bs, mask);
    k_scan  <<<1, 64, 0, stream>>>(mask, remv);
    k_out   <<<N / 256, 256, 0, stream>>>(bs, ss, remv, (float*)d_out);
}

// Round 2
// 516.275 us; speedup vs baseline: 5.4428x; 5.4428x over previous
//
#include <hip/hip_runtime.h>
#include <stdint.h>

#define N 8192

// ---------------- Kernel 1: bitonic sort of composite keys ----------------
// key = (~monotone(score) << 32) | index  -> ascending sort == stable
// argsort of -scores (score desc, index asc on ties).
__global__ __launch_bounds__(1024) void k_sort(const float* __restrict__ scores,
                                               uint32_t* __restrict__ order) {
    __shared__ uint64_t keys[N];
    int t = threadIdx.x;
    for (int e = 0; e < 8; ++e) {
        int i = t + e * 1024;
        uint32_t sb = __float_as_uint(scores[i]);
        sb = (sb & 0x80000000u) ? ~sb : (sb | 0x80000000u);  // ascending-monotone
        keys[i] = ((uint64_t)(~sb) << 32) | (uint32_t)i;     // descending score, asc idx
    }
    __syncthreads();
    for (int k = 2; k <= N; k <<= 1) {
        for (int j = k >> 1; j > 0; j >>= 1) {
            for (int e = 0; e < 8; ++e) {
                int i = t + e * 1024;
                int ixj = i ^ j;
                if (ixj > i) {
                    uint64_t a = keys[i], b = keys[ixj];
                    bool up = ((i & k) == 0);
                    if ((a > b) == up) { keys[i] = b; keys[ixj] = a; }
                }
            }
            __syncthreads();
        }
    }
    for (int e = 0; e < 8; ++e) {
        int i = t + e * 1024;
        order[i] = (uint32_t)keys[i];
    }
}

// ---------------- Kernel 2: gather sorted boxes/scores ----------------
__global__ void k_gather(const float4* __restrict__ boxes,
                         const float* __restrict__ scores,
                         const uint32_t* __restrict__ order,
                         float4* __restrict__ bs, float* __restrict__ ss) {
    int i = blockIdx.x * blockDim.x + threadIdx.x;
    uint32_t j = order[i];
    bs[i] = boxes[j];
    ss[i] = scores[j];
}

// ---------------- Kernel 3: suppression bitmask ----------------
__global__ __launch_bounds__(256) void k_mask(const float4* __restrict__ bs,
                                              uint64_t* __restrict__ mask) {
    __shared__ float4 rb[64];
    __shared__ float  ra[64];
    int R = blockIdx.x & 127;   // row block
    int C = blockIdx.x >> 7;    // col quarter (0..3)
    int t = threadIdx.x;
    int lane = t & 63;
    int wv = t >> 6;
    if (t < 64) {
        float4 b = bs[R * 64 + t];
        rb[t] = b;
        ra[t] = ((b.z - b.x) + 1.0f) * ((b.w - b.y) + 1.0f);
    }
    __syncthreads();
    for (int c = 0; c < 8; ++c) {
        int word = C * 32 + wv * 8 + c;
        int col = word * 64 + lane;
        float4 cb = bs[col];
        float ca = ((cb.z - cb.x) + 1.0f) * ((cb.w - cb.y) + 1.0f);
        for (int r = 0; r < 64; ++r) {
            int row = R * 64 + r;
            float4 rbv = rb[r];
            float ix1 = fmaxf(rbv.x, cb.x);
            float iy1 = fmaxf(rbv.y, cb.y);
            float ix2 = fminf(rbv.z, cb.z);
            float iy2 = fminf(rbv.w, cb.w);
            float iw = fmaxf((ix2 - ix1) + 1.0f, 0.0f);
            float ih = fmaxf((iy2 - iy1) + 1.0f, 0.0f);
            float inter = iw * ih;
            float uni = (ra[r] + ca) - inter;   // matches ref order
            float iou = inter / uni;            // IEEE div, matches numpy ref
            bool pred = (iou > 0.5f) && (col > row);
            uint64_t bal = __ballot(pred);
            if (lane == 0) mask[(size_t)row * 128 + word] = bal;
        }
    }
}

// ---------------- Kernel 4: chunked cooperative greedy scan ----------------
// 1 block x 1024 threads. Chunk = 64 rows. Thread t: row r=t>>4 of chunk,
// holds 8 mask words (pairs at c16*2+32j). Per chunk: wave 0 runs the
// 64-step serial recurrence in registers; all threads OR kept rows' words
// into LDS remv[] for future chunks. Double-buffered reg prefetch (A/B).
__global__ __launch_bounds__(1024) void k_scan(const uint64_t* __restrict__ mask,
                                               uint64_t* __restrict__ keepw) {
    __shared__ uint32_t sh_remv[256];   // remv[w] as lo/hi u32 pairs
    __shared__ uint64_t sh_intra[64];
    __shared__ uint64_t sh_sup;
    int t = threadIdx.x;
    int r = t >> 4;       // row within chunk (0..63)
    int c16 = t & 15;

    if (t < 256) sh_remv[t] = 0;

    uint64_t A[8], B[8];
    {   // prologue: chunk 0 rows into A
        const uint64_t* row0 = mask + (size_t)r * 128;
#pragma unroll
        for (int j = 0; j < 4; ++j) {
            int w = c16 * 2 + 32 * j;
            A[2 * j]     = row0[w];
            A[2 * j + 1] = row0[w + 1];
        }
    }
    __syncthreads();  // remv init visible

#define PROCESS(CHUNK, CUR, NXT)                                               \
    {                                                                          \
        const int c_ = (CHUNK);                                                \
        if (c_ + 1 < 128) {  /* prefetch next chunk rows */                    \
            const uint64_t* rn = mask + ((size_t)(c_ + 1) * 64 + r) * 128;     \
            _Pragma("unroll")                                                  \
            for (int j = 0; j < 4; ++j) {                                      \
                int w = c16 * 2 + 32 * j;                                      \
                NXT[2 * j]     = rn[w];                                        \
                NXT[2 * j + 1] = rn[w + 1];                                    \
            }                                                                  \
        }                                                                      \
        /* stage intra word (global word index == c_) into LDS */              \
        _Pragma("unroll")                                                      \
        for (int j = 0; j < 8; ++j) {                                          \
            int w = c16 * 2 + 32 * (j >> 1) + (j & 1);                         \
            if (w == c_) sh_intra[r] = CUR[j];                                 \
        }                                                                      \
        __syncthreads();                                                       \
        if (t < 64) {  /* wave 0: serial 64-step recurrence */                 \
            uint64_t m_ = sh_intra[t];                                         \
            uint32_t mlo = (uint32_t)m_, mhi = (uint32_t)(m_ >> 32);           \
            uint32_t wlo = __builtin_amdgcn_readfirstlane(sh_remv[2 * c_]);    \
            uint32_t whi = __builtin_amdgcn_readfirstlane(sh_remv[2 * c_ + 1]);\
            uint64_t w_ = ((uint64_t)whi << 32) | wlo;                         \
            _Pragma("unroll")                                                  \
            for (int i = 0; i < 64; ++i) {                                     \
                uint32_t lo = __builtin_amdgcn_readlane(mlo, i);               \
                uint32_t hi = __builtin_amdgcn_readlane(mhi, i);               \
                uint64_t mi = ((uint64_t)hi << 32) | lo;                       \
                w_ |= ((w_ >> i) & 1ull) ? 0ull : mi;                          \
            }                                                                  \
            if (t == 0) { sh_sup = w_; keepw[c_] = ~w_; }                      \
        }                                                                      \
        __syncthreads();                                                       \
        {                                                                      \
            uint64_t sup = sh_sup;                                             \
            bool kept = !((sup >> r) & 1ull);                                  \
            if (kept) {                                                        \
                _Pragma("unroll")                                              \
                for (int j = 0; j < 8; ++j) {                                  \
                    int w = c16 * 2 + 32 * (j >> 1) + (j & 1);                 \
                    uint64_t v = CUR[j];                                       \
                    if (w > c_ && v) {                                         \
                        atomicOr(&sh_remv[2 * w], (uint32_t)v);                \
                        atomicOr(&sh_remv[2 * w + 1], (uint32_t)(v >> 32));    \
                    }                                                          \
                }                                                              \
            }                                                                  \
        }                                                                      \
        __syncthreads();                                                       \
    }

    for (int cc = 0; cc < 128; cc += 2) {
        PROCESS(cc, A, B)
        PROCESS(cc + 1, B, A)
    }
#undef PROCESS
}

// ---------------- Kernel 5: masked outputs ----------------
__global__ void k_out(const float4* __restrict__ bs, const float* __restrict__ ss,
                      const uint64_t* __restrict__ keepw, float* __restrict__ out) {
    int i = blockIdx.x * blockDim.x + threadIdx.x;
    uint64_t wv = keepw[i >> 6];
    float m = ((wv >> (i & 63)) & 1ull) ? 1.0f : 0.0f;
    float4 b = bs[i];
    float4 ob;
    ob.x = b.x * m; ob.y = b.y * m; ob.z = b.z * m; ob.w = b.w * m;
    ((float4*)out)[i] = ob;
    out[4 * N + i] = ss[i] * m;
    out[5 * N + i] = m;
}

extern "C" void kernel_launch(void* const* d_in, const int* in_sizes, int n_in,
                              void* d_out, int out_size, void* d_ws, size_t ws_size,
                              hipStream_t stream) {
    const float* boxes  = (const float*)d_in[0];   // 8192 x 4 f32
    const float* scores = (const float*)d_in[1];   // 8192 f32

    char* ws = (char*)d_ws;
    float4*   bs    = (float4*)(ws + 0);        // 131072 B
    float*    ss    = (float*)(ws + 131072);    //  32768 B
    uint32_t* order = (uint32_t*)(ws + 163840); //  32768 B
    uint64_t* keepw = (uint64_t*)(ws + 196608); //   1024 B
    uint64_t* mask  = (uint64_t*)(ws + 262144); // 8388608 B (8192 rows x 128 words)

    k_sort  <<<1, 1024, 0, stream>>>(scores, order);
    k_gather<<<N / 256, 256, 0, stream>>>((const float4*)boxes, scores, order, bs, ss);
    k_mask  <<<512, 256, 0, stream>>>(bs, mask);
    k_scan  <<<1, 1024, 0, stream>>>(mask, keepw);
    k_out   <<<N / 256, 256, 0, stream>>>(bs, ss, keepw, (float*)d_out);
}

// Round 3
// 328.968 us; speedup vs baseline: 8.5419x; 1.5694x over previous
//
#include <hip/hip_runtime.h>
#include <stdint.h>

#define N 8192

// ---------------- Kernel 1: bitonic sort of composite keys ----------------
// key = (~monotone(score) << 32) | index  -> ascending sort == stable
// argsort of -scores (score desc, index asc on ties).
__global__ __launch_bounds__(1024) void k_sort(const float* __restrict__ scores,
                                               uint32_t* __restrict__ order) {
    __shared__ uint64_t keys[N];
    int t = threadIdx.x;
    for (int e = 0; e < 8; ++e) {
        int i = t + e * 1024;
        uint32_t sb = __float_as_uint(scores[i]);
        sb = (sb & 0x80000000u) ? ~sb : (sb | 0x80000000u);  // ascending-monotone
        keys[i] = ((uint64_t)(~sb) << 32) | (uint32_t)i;     // descending score, asc idx
    }
    __syncthreads();
    for (int k = 2; k <= N; k <<= 1) {
        for (int j = k >> 1; j > 0; j >>= 1) {
            for (int e = 0; e < 8; ++e) {
                int i = t + e * 1024;
                int ixj = i ^ j;
                if (ixj > i) {
                    uint64_t a = keys[i], b = keys[ixj];
                    bool up = ((i & k) == 0);
                    if ((a > b) == up) { keys[i] = b; keys[ixj] = a; }
                }
            }
            __syncthreads();
        }
    }
    for (int e = 0; e < 8; ++e) {
        int i = t + e * 1024;
        order[i] = (uint32_t)keys[i];
    }
}

// ---------------- Kernel 2: gather sorted boxes/scores ----------------
__global__ void k_gather(const float4* __restrict__ boxes,
                         const float* __restrict__ scores,
                         const uint32_t* __restrict__ order,
                         float4* __restrict__ bs, float* __restrict__ ss) {
    int i = blockIdx.x * blockDim.x + threadIdx.x;
    uint32_t j = order[i];
    bs[i] = boxes[j];
    ss[i] = scores[j];
}

// ---------------- Kernel 3: suppression bitmask ----------------
__global__ __launch_bounds__(256) void k_mask(const float4* __restrict__ bs,
                                              uint64_t* __restrict__ mask) {
    __shared__ float4 rb[64];
    __shared__ float  ra[64];
    int R = blockIdx.x & 127;   // row block
    int C = blockIdx.x >> 7;    // col quarter (0..3)
    int t = threadIdx.x;
    int lane = t & 63;
    int wv = t >> 6;
    if (t < 64) {
        float4 b = bs[R * 64 + t];
        rb[t] = b;
        ra[t] = ((b.z - b.x) + 1.0f) * ((b.w - b.y) + 1.0f);
    }
    __syncthreads();
    for (int c = 0; c < 8; ++c) {
        int word = C * 32 + wv * 8 + c;
        int col = word * 64 + lane;
        float4 cb = bs[col];
        float ca = ((cb.z - cb.x) + 1.0f) * ((cb.w - cb.y) + 1.0f);
        for (int r = 0; r < 64; ++r) {
            int row = R * 64 + r;
            float4 rbv = rb[r];
            float ix1 = fmaxf(rbv.x, cb.x);
            float iy1 = fmaxf(rbv.y, cb.y);
            float ix2 = fminf(rbv.z, cb.z);
            float iy2 = fminf(rbv.w, cb.w);
            float iw = fmaxf((ix2 - ix1) + 1.0f, 0.0f);
            float ih = fmaxf((iy2 - iy1) + 1.0f, 0.0f);
            float inter = iw * ih;
            float uni = (ra[r] + ca) - inter;   // matches ref order
            float iou = inter / uni;            // IEEE div, matches numpy ref
            bool pred = (iou > 0.5f) && (col > row);
            uint64_t bal = __ballot(pred);
            if (lane == 0) mask[(size_t)row * 128 + word] = bal;
        }
    }
}

// ---------------- Kernel 4: chunked cooperative greedy scan ----------------
// 512 threads. Chunk = 64 rows. Thread t: row r=t>>3, c8=t&7 holds 16 mask
// words as 8 x ulonglong2 (pairs at word c8*2+16k). Light barriers (lgkmcnt
// only) keep prefetch loads in flight across chunks (T4). Serial recurrence
// runs sparse: only rows with nonzero intra-chunk word, as a scalar
// s_ff1/readlane chain (~11 steps/chunk on random boxes instead of 64).
__global__ __launch_bounds__(512) void k_scan(const uint64_t* __restrict__ mask,
                                              uint64_t* __restrict__ keepw) {
    __shared__ uint64_t sh_remv[128];
    __shared__ uint64_t sh_intra[64];
    __shared__ uint64_t sh_sup;
    const int t = threadIdx.x;
    const int r = t >> 3;
    const int c8 = t & 7;

    if (t < 128) sh_remv[t] = 0;

    ulonglong2 A[8], B[8];
    uint64_t dA = 0, dB = 0;
    {
        const ulonglong2* row0 = (const ulonglong2*)(mask + (size_t)r * 128);
#pragma unroll
        for (int k = 0; k < 8; ++k) A[k] = row0[c8 + 8 * k];
        if (t < 64) {
            sh_intra[t] = mask[(size_t)t * 128];        // chunk 0 diag word (w=0)
            dA = mask[((size_t)64 + t) * 128 + 1];      // chunk 1 diag word (w=1)
        }
    }
    __syncthreads();

#define LBAR() do { asm volatile("s_waitcnt lgkmcnt(0)" ::: "memory"); \
                    __builtin_amdgcn_s_barrier(); } while (0)

#define PROCESS(C_, CUR, NXT, DC, DN)                                          \
    {                                                                          \
        const int c_ = (C_);                                                   \
        if (c_ + 1 < 128) {  /* prefetch next chunk's rows */                  \
            const ulonglong2* rn =                                             \
                (const ulonglong2*)(mask + ((size_t)(c_ + 1) * 64 + r) * 128); \
            _Pragma("unroll")                                                  \
            for (int k = 0; k < 8; ++k) NXT[k] = rn[c8 + 8 * k];               \
        }                                                                      \
        if (c_ + 2 < 128 && t < 64)  /* 2-deep diag prefetch */                \
            DN = mask[((size_t)(c_ + 2) * 64 + t) * 128 + (c_ + 2)];           \
        LBAR();                                                                \
        if (t < 64) {  /* wave 0: sparse scalar serial recurrence */           \
            uint64_t m_ = sh_intra[t];                                         \
            uint64_t nzv = __ballot(m_ != 0);                                  \
            uint32_t nlo = __builtin_amdgcn_readfirstlane((uint32_t)nzv);      \
            uint32_t nhi = __builtin_amdgcn_readfirstlane((uint32_t)(nzv>>32));\
            uint64_t nz = ((uint64_t)nhi << 32) | nlo;                         \
            uint32_t mlo = (uint32_t)m_, mhi = (uint32_t)(m_ >> 32);           \
            uint64_t wv = sh_remv[c_];                                         \
            uint32_t wlo = __builtin_amdgcn_readfirstlane((uint32_t)wv);       \
            uint32_t whi = __builtin_amdgcn_readfirstlane((uint32_t)(wv>>32)); \
            uint64_t w_ = ((uint64_t)whi << 32) | wlo;                         \
            while (nz) {                                                       \
                int i = (int)__builtin_ctzll(nz);                              \
                nz &= nz - 1;                                                  \
                if (!((w_ >> i) & 1ull)) {                                     \
                    uint32_t lo = __builtin_amdgcn_readlane(mlo, i);           \
                    uint32_t hi = __builtin_amdgcn_readlane(mhi, i);           \
                    w_ |= ((uint64_t)hi << 32) | lo;                           \
                }                                                              \
            }                                                                  \
            if (t == 0) { sh_sup = w_; keepw[c_] = ~w_; }                      \
        }                                                                      \
        LBAR();                                                                \
        {  /* suppression OR for future words + stage next intra */            \
            uint64_t sup = sh_sup;                                             \
            if (!((sup >> r) & 1ull)) {                                        \
                _Pragma("unroll")                                              \
                for (int k = 0; k < 8; ++k) {                                  \
                    int w0 = c8 * 2 + 16 * k;                                  \
                    uint64_t v0 = CUR[k].x, v1 = CUR[k].y;                     \
                    if (w0 > c_ && v0)                                         \
                        atomicOr((unsigned long long*)&sh_remv[w0],            \
                                 (unsigned long long)v0);                      \
                    if (w0 + 1 > c_ && v1)                                     \
                        atomicOr((unsigned long long*)&sh_remv[w0 + 1],        \
                                 (unsigned long long)v1);                      \
                }                                                              \
            }                                                                  \
            if (c_ + 1 < 128 && t < 64) sh_intra[t] = DC;                      \
        }                                                                      \
    }

    for (int cc = 0; cc < 128; cc += 2) {
        PROCESS(cc, A, B, dA, dB)
        PROCESS(cc + 1, B, A, dB, dA)
    }
#undef PROCESS
#undef LBAR
}

// ---------------- Kernel 5: masked outputs ----------------
__global__ void k_out(const float4* __restrict__ bs, const float* __restrict__ ss,
                      const uint64_t* __restrict__ keepw, float* __restrict__ out) {
    int i = blockIdx.x * blockDim.x + threadIdx.x;
    uint64_t wv = keepw[i >> 6];
    float m = ((wv >> (i & 63)) & 1ull) ? 1.0f : 0.0f;
    float4 b = bs[i];
    float4 ob;
    ob.x = b.x * m; ob.y = b.y * m; ob.z = b.z * m; ob.w = b.w * m;
    ((float4*)out)[i] = ob;
    out[4 * N + i] = ss[i] * m;
    out[5 * N + i] = m;
}

extern "C" void kernel_launch(void* const* d_in, const int* in_sizes, int n_in,
                              void* d_out, int out_size, void* d_ws, size_t ws_size,
                              hipStream_t stream) {
    const float* boxes  = (const float*)d_in[0];   // 8192 x 4 f32
    const float* scores = (const float*)d_in[1];   // 8192 f32

    char* ws = (char*)d_ws;
    float4*   bs    = (float4*)(ws + 0);        // 131072 B
    float*    ss    = (float*)(ws + 131072);    //  32768 B
    uint32_t* order = (uint32_t*)(ws + 163840); //  32768 B
    uint64_t* keepw = (uint64_t*)(ws + 196608); //   1024 B
    uint64_t* mask  = (uint64_t*)(ws + 262144); // 8388608 B (8192 rows x 128 words)

    k_sort  <<<1, 1024, 0, stream>>>(scores, order);
    k_gather<<<N / 256, 256, 0, stream>>>((const float4*)boxes, scores, order, bs, ss);
    k_mask  <<<512, 256, 0, stream>>>(bs, mask);
    k_scan  <<<1, 512, 0, stream>>>(mask, keepw);
    k_out   <<<N / 256, 256, 0, stream>>>(bs, ss, keepw, (float*)d_out);
}

// Round 4
// 305.808 us; speedup vs baseline: 9.1888x; 1.0757x over previous
//
#include <hip/hip_runtime.h>
#include <stdint.h>

#define N 8192

// ================= Sort stage (bitonic, exact argsort) =================
// key = (~monotone(score) << 32) | index; ascending sort == stable argsort
// of -scores. Network split: local k<=2048 (s1), k=4096 (s2), k=8192 (s3).

__global__ __launch_bounds__(1024) void k_sort1(const float* __restrict__ scores,
                                                uint64_t* __restrict__ keys) {
    __shared__ uint64_t sk[2048];
    int b = blockIdx.x, t = threadIdx.x;
    int base = b * 2048;
    for (int e = 0; e < 2; ++e) {
        int li = t + e * 1024;
        int i = base + li;
        uint32_t sb = __float_as_uint(scores[i]);
        sb = (sb & 0x80000000u) ? ~sb : (sb | 0x80000000u);
        sk[li] = ((uint64_t)(~sb) << 32) | (uint32_t)i;
    }
    __syncthreads();
    for (int k = 2; k <= 2048; k <<= 1) {
        for (int j = k >> 1; j > 0; j >>= 1) {
            for (int e = 0; e < 2; ++e) {
                int li = t + e * 1024;
                int lixj = li ^ j;
                if (lixj > li) {
                    int gi = base + li;
                    bool up = ((gi & k) == 0);
                    uint64_t a = sk[li], c = sk[lixj];
                    if ((a > c) == up) { sk[li] = c; sk[lixj] = a; }
                }
            }
            __syncthreads();
        }
    }
    for (int e = 0; e < 2; ++e) { int li = t + e * 1024; keys[base + li] = sk[li]; }
}

// k=4096: cross pass j=2048 read from global (element-wise), then local j<=1024.
__global__ __launch_bounds__(1024) void k_sort2(const uint64_t* __restrict__ keys,
                                                uint64_t* __restrict__ keys2) {
    __shared__ uint64_t sk[2048];
    int b = blockIdx.x, t = threadIdx.x;
    int base = b * 2048;
    for (int e = 0; e < 2; ++e) {
        int li = t + e * 1024;
        int i = base + li;
        uint64_t a = keys[i], c = keys[i ^ 2048];
        bool up = ((i & 4096) == 0);
        bool lowpos = ((i & 2048) == 0);
        uint64_t mn = a < c ? a : c, mx = a < c ? c : a;
        sk[li] = (up == lowpos) ? mn : mx;
    }
    __syncthreads();
    for (int j = 1024; j > 0; j >>= 1) {
        for (int e = 0; e < 2; ++e) {
            int li = t + e * 1024;
            int lixj = li ^ j;
            if (lixj > li) {
                int gi = base + li;
                bool up = ((gi & 4096) == 0);
                uint64_t a = sk[li], c = sk[lixj];
                if ((a > c) == up) { sk[li] = c; sk[lixj] = a; }
            }
        }
        __syncthreads();
    }
    for (int e = 0; e < 2; ++e) { int li = t + e * 1024; keys2[base + li] = sk[li]; }
}

// k=8192 (up=true everywhere): cross passes j=4096,2048 from global, local
// j<=1024, then fused gather of boxes/scores into sorted order.
__global__ __launch_bounds__(1024) void k_sort3(const uint64_t* __restrict__ keys2,
                                                const float4* __restrict__ boxes,
                                                const float* __restrict__ scores,
                                                float4* __restrict__ bs,
                                                float* __restrict__ ss) {
    __shared__ uint64_t sk[2048];
    int b = blockIdx.x, t = threadIdx.x;
    int base = b * 2048;
    for (int e = 0; e < 2; ++e) {
        int li = t + e * 1024;
        int i = base + li;
        uint64_t a0 = keys2[i], a1 = keys2[i ^ 4096];
        bool low0 = ((i & 4096) == 0);
        uint64_t v = low0 ? (a0 < a1 ? a0 : a1) : (a0 < a1 ? a1 : a0);
        int q = i ^ 2048;
        uint64_t b0 = keys2[q], b1 = keys2[q ^ 4096];
        bool lowq = ((q & 4096) == 0);
        uint64_t vq = lowq ? (b0 < b1 ? b0 : b1) : (b0 < b1 ? b1 : b0);
        bool low2 = ((i & 2048) == 0);
        sk[li] = low2 ? (v < vq ? v : vq) : (v < vq ? vq : v);
    }
    __syncthreads();
    for (int j = 1024; j > 0; j >>= 1) {
        for (int e = 0; e < 2; ++e) {
            int li = t + e * 1024;
            int lixj = li ^ j;
            if (lixj > li) {
                uint64_t a = sk[li], c = sk[lixj];
                if (a > c) { sk[li] = c; sk[lixj] = a; }   // up = true
            }
        }
        __syncthreads();
    }
    for (int e = 0; e < 2; ++e) {
        int li = t + e * 1024;
        int gi = base + li;
        uint32_t idx = (uint32_t)sk[li];
        bs[gi] = boxes[idx];
        ss[gi] = scores[idx];
    }
}

// ---------------- Suppression bitmask (upper triangle only) ----------------
__global__ __launch_bounds__(256) void k_mask(const float4* __restrict__ bs,
                                              uint64_t* __restrict__ mask) {
    __shared__ float4 rb[64];
    __shared__ float  ra[64];
    int R = blockIdx.x & 127;   // row block == chunk index
    int C = blockIdx.x >> 7;    // col quarter (0..3)
    if (32 * C + 31 < R) return;   // entire block below diagonal: never read
    int t = threadIdx.x;
    int lane = t & 63;
    int wv = t >> 6;
    if (t < 64) {
        float4 b = bs[R * 64 + t];
        rb[t] = b;
        ra[t] = ((b.z - b.x) + 1.0f) * ((b.w - b.y) + 1.0f);
    }
    __syncthreads();
    for (int c = 0; c < 8; ++c) {
        int word = C * 32 + wv * 8 + c;
        if (word < R) continue;     // sub-diagonal word: never read
        int col = word * 64 + lane;
        float4 cb = bs[col];
        float ca = ((cb.z - cb.x) + 1.0f) * ((cb.w - cb.y) + 1.0f);
        for (int r = 0; r < 64; ++r) {
            int row = R * 64 + r;
            float4 rbv = rb[r];
            float ix1 = fmaxf(rbv.x, cb.x);
            float iy1 = fmaxf(rbv.y, cb.y);
            float ix2 = fminf(rbv.z, cb.z);
            float iy2 = fminf(rbv.w, cb.w);
            float iw = fmaxf((ix2 - ix1) + 1.0f, 0.0f);
            float ih = fmaxf((iy2 - iy1) + 1.0f, 0.0f);
            float inter = iw * ih;
            float uni = (ra[r] + ca) - inter;   // matches ref order
            float iou = inter / uni;            // IEEE div, matches numpy ref
            bool pred = (iou > 0.5f) && (col > row);
            uint64_t bal = __ballot(pred);
            if (lane == 0) mask[(size_t)row * 128 + word] = bal;
        }
    }
}

// ---------------- Chunked cooperative greedy scan ----------------
// 1024 threads. Thread t: row r=t>>4, c16=t&15 holds 8 words (4 x ulonglong2).
// Triangular prefetch: only pairs with w1 >= chunk are loaded (rows only ever
// contribute words > their chunk). Light barriers keep global loads in flight.
__global__ __launch_bounds__(1024) void k_scan(const uint64_t* __restrict__ mask,
                                               uint64_t* __restrict__ keepw) {
    __shared__ uint64_t sh_remv[128];
    __shared__ uint64_t sh_intra[64];
    __shared__ uint64_t sh_sup;
    const int t = threadIdx.x;
    const int r = t >> 4;
    const int c16 = t & 15;

    if (t < 128) sh_remv[t] = 0;

    ulonglong2 A[4], B[4];
    uint64_t dA = 0, dB = 0;
    {
        const ulonglong2* row0 = (const ulonglong2*)(mask + (size_t)r * 128);
#pragma unroll
        for (int k = 0; k < 4; ++k) A[k] = row0[c16 + 16 * k];
        if (t < 64) {
            sh_intra[t] = mask[(size_t)t * 128];        // chunk 0 diag word
            dA = mask[((size_t)64 + t) * 128 + 1];      // chunk 1 diag word
        }
    }
    __syncthreads();

#define LBAR() do { asm volatile("s_waitcnt lgkmcnt(0)" ::: "memory"); \
                    __builtin_amdgcn_s_barrier(); } while (0)

#define PROCESS(C_, CUR, NXT, DC, DN)                                          \
    {                                                                          \
        const int c_ = (C_);                                                   \
        if (c_ + 1 < 128) {  /* triangular prefetch of next chunk's rows */    \
            const ulonglong2* rn =                                             \
                (const ulonglong2*)(mask + ((size_t)(c_ + 1) * 64 + r) * 128); \
            _Pragma("unroll")                                                  \
            for (int k = 0; k < 4; ++k) {                                      \
                int p = c16 + 16 * k;                                          \
                if (2 * p + 1 >= c_ + 1) NXT[k] = rn[p];                       \
            }                                                                  \
        }                                                                      \
        if (c_ + 2 < 128 && t < 64)  /* 2-deep diag prefetch */                \
            DN = mask[((size_t)(c_ + 2) * 64 + t) * 128 + (c_ + 2)];           \
        LBAR();                                                                \
        if (t < 64) {  /* wave 0: sparse scalar serial recurrence */           \
            uint64_t m_ = sh_intra[t];                                         \
            uint64_t nzv = __ballot(m_ != 0);                                  \
            uint32_t nlo = __builtin_amdgcn_readfirstlane((uint32_t)nzv);      \
            uint32_t nhi = __builtin_amdgcn_readfirstlane((uint32_t)(nzv>>32));\
            uint64_t nz = ((uint64_t)nhi << 32) | nlo;                         \
            uint32_t mlo = (uint32_t)m_, mhi = (uint32_t)(m_ >> 32);           \
            uint64_t wv = sh_remv[c_];                                         \
            uint32_t wlo = __builtin_amdgcn_readfirstlane((uint32_t)wv);       \
            uint32_t whi = __builtin_amdgcn_readfirstlane((uint32_t)(wv>>32)); \
            uint64_t w_ = ((uint64_t)whi << 32) | wlo;                         \
            while (nz) {                                                       \
                int i = (int)__builtin_ctzll(nz);                              \
                nz &= nz - 1;                                                  \
                if (!((w_ >> i) & 1ull)) {                                     \
                    uint32_t lo = __builtin_amdgcn_readlane(mlo, i);           \
                    uint32_t hi = __builtin_amdgcn_readlane(mhi, i);           \
                    w_ |= ((uint64_t)hi << 32) | lo;                           \
                }                                                              \
            }                                                                  \
            if (t == 0) { sh_sup = w_; keepw[c_] = ~w_; }                      \
        }                                                                      \
        LBAR();                                                                \
        {  /* suppression OR for future words + stage next intra */            \
            uint64_t sup = sh_sup;                                             \
            if (!((sup >> r) & 1ull)) {                                        \
                _Pragma("unroll")                                              \
                for (int k = 0; k < 4; ++k) {                                  \
                    int w0 = 2 * (c16 + 16 * k);                               \
                    uint64_t v0 = CUR[k].x, v1 = CUR[k].y;                     \
                    if (w0 > c_ && v0)                                         \
                        atomicOr((unsigned long long*)&sh_remv[w0],            \
                                 (unsigned long long)v0);                      \
                    if (w0 + 1 > c_ && v1)                                     \
                        atomicOr((unsigned long long*)&sh_remv[w0 + 1],        \
                                 (unsigned long long)v1);                      \
                }                                                              \
            }                                                                  \
            if (c_ + 1 < 128 && t < 64) sh_intra[t] = DC;                      \
        }                                                                      \
    }

    for (int cc = 0; cc < 128; cc += 2) {
        PROCESS(cc, A, B, dA, dB)
        PROCESS(cc + 1, B, A, dB, dA)
    }
#undef PROCESS
#undef LBAR
}

// ---------------- Masked outputs ----------------
__global__ void k_out(const float4* __restrict__ bs, const float* __restrict__ ss,
                      const uint64_t* __restrict__ keepw, float* __restrict__ out) {
    int i = blockIdx.x * blockDim.x + threadIdx.x;
    uint64_t wv = keepw[i >> 6];
    float m = ((wv >> (i & 63)) & 1ull) ? 1.0f : 0.0f;
    float4 b = bs[i];
    float4 ob;
    ob.x = b.x * m; ob.y = b.y * m; ob.z = b.z * m; ob.w = b.w * m;
    ((float4*)out)[i] = ob;
    out[4 * N + i] = ss[i] * m;
    out[5 * N + i] = m;
}

extern "C" void kernel_launch(void* const* d_in, const int* in_sizes, int n_in,
                              void* d_out, int out_size, void* d_ws, size_t ws_size,
                              hipStream_t stream) {
    const float* boxes  = (const float*)d_in[0];   // 8192 x 4 f32
    const float* scores = (const float*)d_in[1];   // 8192 f32

    char* ws = (char*)d_ws;
    float4*   bs    = (float4*)(ws + 0);        // 131072 B
    float*    ss    = (float*)(ws + 131072);    //  32768 B
    uint64_t* keepw = (uint64_t*)(ws + 163840); //   1024 B
    uint64_t* mask  = (uint64_t*)(ws + 262144); // 8388608 B (8192 rows x 128 words)
    // keys/keys2 overlap the mask region: sort finishes before k_mask writes it.
    uint64_t* keys  = (uint64_t*)(ws + 262144);
    uint64_t* keys2 = (uint64_t*)(ws + 262144 + 65536);

    k_sort1<<<4, 1024, 0, stream>>>(scores, keys);
    k_sort2<<<4, 1024, 0, stream>>>(keys, keys2);
    k_sort3<<<4, 1024, 0, stream>>>(keys2, (const float4*)boxes, scores, bs, ss);
    k_mask <<<512, 256, 0, stream>>>(bs, mask);
    k_scan <<<1, 1024, 0, stream>>>(mask, keepw);
    k_out  <<<N / 256, 256, 0, stream>>>(bs, ss, keepw, (float*)d_out);
}

// Round 5
// 263.158 us; speedup vs baseline: 10.6780x; 1.1621x over previous
//
#include <hip/hip_runtime.h>
#include <stdint.h>

#define N 8192

// ================= Sort stage (bitonic, exact argsort) =================
// key = (~monotone(score) << 32) | index; ascending sort == stable argsort
// of -scores. Network split: local k<=2048 (s1), k=4096 (s2), k=8192 (s3).

__global__ __launch_bounds__(1024) void k_sort1(const float* __restrict__ scores,
                                                uint64_t* __restrict__ keys) {
    __shared__ uint64_t sk[2048];
    int b = blockIdx.x, t = threadIdx.x;
    int base = b * 2048;
    for (int e = 0; e < 2; ++e) {
        int li = t + e * 1024;
        int i = base + li;
        uint32_t sb = __float_as_uint(scores[i]);
        sb = (sb & 0x80000000u) ? ~sb : (sb | 0x80000000u);
        sk[li] = ((uint64_t)(~sb) << 32) | (uint32_t)i;
    }
    __syncthreads();
    for (int k = 2; k <= 2048; k <<= 1) {
        for (int j = k >> 1; j > 0; j >>= 1) {
            for (int e = 0; e < 2; ++e) {
                int li = t + e * 1024;
                int lixj = li ^ j;
                if (lixj > li) {
                    int gi = base + li;
                    bool up = ((gi & k) == 0);
                    uint64_t a = sk[li], c = sk[lixj];
                    if ((a > c) == up) { sk[li] = c; sk[lixj] = a; }
                }
            }
            __syncthreads();
        }
    }
    for (int e = 0; e < 2; ++e) { int li = t + e * 1024; keys[base + li] = sk[li]; }
}

// k=4096: cross pass j=2048 read from global (element-wise), then local j<=1024.
__global__ __launch_bounds__(1024) void k_sort2(const uint64_t* __restrict__ keys,
                                                uint64_t* __restrict__ keys2) {
    __shared__ uint64_t sk[2048];
    int b = blockIdx.x, t = threadIdx.x;
    int base = b * 2048;
    for (int e = 0; e < 2; ++e) {
        int li = t + e * 1024;
        int i = base + li;
        uint64_t a = keys[i], c = keys[i ^ 2048];
        bool up = ((i & 4096) == 0);
        bool lowpos = ((i & 2048) == 0);
        uint64_t mn = a < c ? a : c, mx = a < c ? c : a;
        sk[li] = (up == lowpos) ? mn : mx;
    }
    __syncthreads();
    for (int j = 1024; j > 0; j >>= 1) {
        for (int e = 0; e < 2; ++e) {
            int li = t + e * 1024;
            int lixj = li ^ j;
            if (lixj > li) {
                int gi = base + li;
                bool up = ((gi & 4096) == 0);
                uint64_t a = sk[li], c = sk[lixj];
                if ((a > c) == up) { sk[li] = c; sk[lixj] = a; }
            }
        }
        __syncthreads();
    }
    for (int e = 0; e < 2; ++e) { int li = t + e * 1024; keys2[base + li] = sk[li]; }
}

// k=8192 (up=true everywhere): cross passes j=4096,2048 from global, local
// j<=1024, then fused gather of boxes/scores into sorted order.
__global__ __launch_bounds__(1024) void k_sort3(const uint64_t* __restrict__ keys2,
                                                const float4* __restrict__ boxes,
                                                const float* __restrict__ scores,
                                                float4* __restrict__ bs,
                                                float* __restrict__ ss) {
    __shared__ uint64_t sk[2048];
    int b = blockIdx.x, t = threadIdx.x;
    int base = b * 2048;
    for (int e = 0; e < 2; ++e) {
        int li = t + e * 1024;
        int i = base + li;
        uint64_t a0 = keys2[i], a1 = keys2[i ^ 4096];
        bool low0 = ((i & 4096) == 0);
        uint64_t v = low0 ? (a0 < a1 ? a0 : a1) : (a0 < a1 ? a1 : a0);
        int q = i ^ 2048;
        uint64_t b0 = keys2[q], b1 = keys2[q ^ 4096];
        bool lowq = ((q & 4096) == 0);
        uint64_t vq = lowq ? (b0 < b1 ? b0 : b1) : (b0 < b1 ? b1 : b0);
        bool low2 = ((i & 2048) == 0);
        sk[li] = low2 ? (v < vq ? v : vq) : (v < vq ? vq : v);
    }
    __syncthreads();
    for (int j = 1024; j > 0; j >>= 1) {
        for (int e = 0; e < 2; ++e) {
            int li = t + e * 1024;
            int lixj = li ^ j;
            if (lixj > li) {
                uint64_t a = sk[li], c = sk[lixj];
                if (a > c) { sk[li] = c; sk[lixj] = a; }   // up = true
            }
        }
        __syncthreads();
    }
    for (int e = 0; e < 2; ++e) {
        int li = t + e * 1024;
        int gi = base + li;
        uint32_t idx = (uint32_t)sk[li];
        bs[gi] = boxes[idx];
        ss[gi] = scores[idx];
    }
}

// ---------------- Suppression bitmask (upper triangle only) ----------------
__global__ __launch_bounds__(256) void k_mask(const float4* __restrict__ bs,
                                              uint64_t* __restrict__ mask) {
    __shared__ float4 rb[64];
    __shared__ float  ra[64];
    int R = blockIdx.x & 127;   // row block == chunk index
    int C = blockIdx.x >> 7;    // col quarter (0..3)
    if (32 * C + 31 < R) return;   // entire block below diagonal: never read
    int t = threadIdx.x;
    int lane = t & 63;
    int wv = t >> 6;
    if (t < 64) {
        float4 b = bs[R * 64 + t];
        rb[t] = b;
        ra[t] = ((b.z - b.x) + 1.0f) * ((b.w - b.y) + 1.0f);
    }
    __syncthreads();
    for (int c = 0; c < 8; ++c) {
        int word = C * 32 + wv * 8 + c;
        if (word < R) continue;     // sub-diagonal word: never read
        int col = word * 64 + lane;
        float4 cb = bs[col];
        float ca = ((cb.z - cb.x) + 1.0f) * ((cb.w - cb.y) + 1.0f);
        for (int r = 0; r < 64; ++r) {
            int row = R * 64 + r;
            float4 rbv = rb[r];
            float ix1 = fmaxf(rbv.x, cb.x);
            float iy1 = fmaxf(rbv.y, cb.y);
            float ix2 = fminf(rbv.z, cb.z);
            float iy2 = fminf(rbv.w, cb.w);
            float iw = fmaxf((ix2 - ix1) + 1.0f, 0.0f);
            float ih = fmaxf((iy2 - iy1) + 1.0f, 0.0f);
            float inter = iw * ih;
            float uni = (ra[r] + ca) - inter;   // matches ref order
            float iou = inter / uni;            // IEEE div, matches numpy ref
            bool pred = (iou > 0.5f) && (col > row);
            uint64_t bal = __ballot(pred);
            if (lane == 0) mask[(size_t)row * 128 + word] = bal;
        }
    }
}

// ---------------- Chunked cooperative greedy scan ----------------
// 512 threads (8 waves). Thread t: row r=t>>3, c8=t&7 holds 16 words
// (8 x ulonglong2, ungated — garbage sub-diagonal words are dead via the
// w0 > c_ gate). ONE light barrier per chunk: every wave computes the
// serial recurrence redundantly from wave-uniform scalars, so `sup` is
// already in registers for the suppression phase (no sh_sup round-trip,
// no second barrier, no idle waves). sh_intra double-buffered.
__global__ __launch_bounds__(512) void k_scan(const uint64_t* __restrict__ mask,
                                              uint64_t* __restrict__ keepw) {
    __shared__ uint64_t sh_remv[128];
    __shared__ uint64_t sh_intra[2][64];
    const int t = threadIdx.x;
    const int r = t >> 3;
    const int c8 = t & 7;
    const int lane = t & 63;

    if (t < 128) sh_remv[t] = 0;

    ulonglong2 A[8], B[8];
    uint64_t dA = 0, dB = 0;
    {
        const ulonglong2* row0 = (const ulonglong2*)(mask + (size_t)r * 128);
#pragma unroll
        for (int k = 0; k < 8; ++k) A[k] = row0[c8 + 8 * k];
        if (t < 64) {
            sh_intra[0][t] = mask[(size_t)t * 128];     // chunk 0 diag word
            dA = mask[((size_t)64 + t) * 128 + 1];      // chunk 1 diag word
        }
    }
    __syncthreads();

#define LBAR() do { asm volatile("s_waitcnt lgkmcnt(0)" ::: "memory"); \
                    __builtin_amdgcn_s_barrier(); } while (0)

#define PROCESS(C_, CUR, NXT, DC, DN, PAR)                                     \
    {                                                                          \
        const int c_ = (C_);                                                   \
        if (c_ + 1 < 128) {  /* prefetch next chunk's rows (ungated) */        \
            const ulonglong2* rn =                                             \
                (const ulonglong2*)(mask + ((size_t)(c_ + 1) * 64 + r) * 128); \
            _Pragma("unroll")                                                  \
            for (int k = 0; k < 8; ++k) NXT[k] = rn[c8 + 8 * k];               \
        }                                                                      \
        if (c_ + 2 < 128 && t < 64)  /* 2-deep diag prefetch */                \
            DN = mask[((size_t)(c_ + 2) * 64 + t) * 128 + (c_ + 2)];           \
        LBAR();                                                                \
        uint64_t w_;                                                           \
        {  /* ALL waves: redundant sparse scalar serial recurrence */          \
            uint64_t m_ = sh_intra[PAR][lane];                                 \
            uint64_t nzv = __ballot(m_ != 0);                                  \
            uint32_t nlo = __builtin_amdgcn_readfirstlane((uint32_t)nzv);      \
            uint32_t nhi = __builtin_amdgcn_readfirstlane((uint32_t)(nzv>>32));\
            uint64_t nz = ((uint64_t)nhi << 32) | nlo;                         \
            uint32_t mlo = (uint32_t)m_, mhi = (uint32_t)(m_ >> 32);           \
            uint64_t wv = sh_remv[c_];                                         \
            uint32_t wlo = __builtin_amdgcn_readfirstlane((uint32_t)wv);       \
            uint32_t whi = __builtin_amdgcn_readfirstlane((uint32_t)(wv>>32)); \
            w_ = ((uint64_t)whi << 32) | wlo;                                  \
            while (nz) {                                                       \
                int i = (int)__builtin_ctzll(nz);                              \
                nz &= nz - 1;                                                  \
                if (!((w_ >> i) & 1ull)) {                                     \
                    uint32_t lo = __builtin_amdgcn_readlane(mlo, i);           \
                    uint32_t hi = __builtin_amdgcn_readlane(mhi, i);           \
                    w_ |= ((uint64_t)hi << 32) | lo;                           \
                }                                                              \
            }                                                                  \
            if (t == 0) keepw[c_] = ~w_;                                       \
        }                                                                      \
        {  /* suppression OR for future words + stage next intra */            \
            if (!((w_ >> r) & 1ull)) {                                         \
                _Pragma("unroll")                                              \
                for (int k = 0; k < 8; ++k) {                                  \
                    int w0 = 2 * (c8 + 8 * k);                                 \
                    uint64_t v0 = CUR[k].x, v1 = CUR[k].y;                     \
                    if (w0 > c_ && v0)                                         \
                        atomicOr((unsigned long long*)&sh_remv[w0],            \
                                 (unsigned long long)v0);                      \
                    if (w0 + 1 > c_ && v1)                                     \
                        atomicOr((unsigned long long*)&sh_remv[w0 + 1],        \
                                 (unsigned long long)v1);                      \
                }                                                              \
            }                                                                  \
            if (c_ + 1 < 128 && t < 64) sh_intra[1 - PAR][t] = DC;             \
        }                                                                      \
    }

    for (int cc = 0; cc < 128; cc += 2) {
        PROCESS(cc, A, B, dA, dB, 0)
        PROCESS(cc + 1, B, A, dB, dA, 1)
    }
#undef PROCESS
#undef LBAR
}

// ---------------- Masked outputs ----------------
__global__ void k_out(const float4* __restrict__ bs, const float* __restrict__ ss,
                      const uint64_t* __restrict__ keepw, float* __restrict__ out) {
    int i = blockIdx.x * blockDim.x + threadIdx.x;
    uint64_t wv = keepw[i >> 6];
    float m = ((wv >> (i & 63)) & 1ull) ? 1.0f : 0.0f;
    float4 b = bs[i];
    float4 ob;
    ob.x = b.x * m; ob.y = b.y * m; ob.z = b.z * m; ob.w = b.w * m;
    ((float4*)out)[i] = ob;
    out[4 * N + i] = ss[i] * m;
    out[5 * N + i] = m;
}

extern "C" void kernel_launch(void* const* d_in, const int* in_sizes, int n_in,
                              void* d_out, int out_size, void* d_ws, size_t ws_size,
                              hipStream_t stream) {
    const float* boxes  = (const float*)d_in[0];   // 8192 x 4 f32
    const float* scores = (const float*)d_in[1];   // 8192 f32

    char* ws = (char*)d_ws;
    float4*   bs    = (float4*)(ws + 0);        // 131072 B
    float*    ss    = (float*)(ws + 131072);    //  32768 B
    uint64_t* keepw = (uint64_t*)(ws + 163840); //   1024 B
    uint64_t* mask  = (uint64_t*)(ws + 262144); // 8388608 B (8192 rows x 128 words)
    // keys/keys2 overlap the mask region: sort finishes before k_mask writes it.
    uint64_t* keys  = (uint64_t*)(ws + 262144);
    uint64_t* keys2 = (uint64_t*)(ws + 262144 + 65536);

    k_sort1<<<4, 1024, 0, stream>>>(scores, keys);
    k_sort2<<<4, 1024, 0, stream>>>(keys, keys2);
    k_sort3<<<4, 1024, 0, stream>>>(keys2, (const float4*)boxes, scores, bs, ss);
    k_mask <<<512, 256, 0, stream>>>(bs, mask);
    k_scan <<<1, 512, 0, stream>>>(mask, keepw);
    k_out  <<<N / 256, 256, 0, stream>>>(bs, ss, keepw, (float*)d_out);
}

// Round 6
// 248.782 us; speedup vs baseline: 11.2950x; 1.0578x over previous
//
#include <hip/hip_runtime.h>
#include <stdint.h>

#define N 8192
#define CAP 16

// ================= Sort stage (bitonic, exact argsort) =================
// key = (~monotone(score) << 32) | index; ascending sort == stable argsort
// of -scores. Network split: local k<=2048 (s1), k=4096 (s2), k=8192 (s3).

__global__ __launch_bounds__(1024) void k_sort1(const float* __restrict__ scores,
                                                uint64_t* __restrict__ keys,
                                                uint32_t* __restrict__ cnt) {
    __shared__ uint64_t sk[2048];
    int b = blockIdx.x, t = threadIdx.x;
    int base = b * 2048;
    // zero the per-row packed-entry counters (must happen before k_mask).
    cnt[base + t] = 0;
    cnt[base + t + 1024] = 0;
    for (int e = 0; e < 2; ++e) {
        int li = t + e * 1024;
        int i = base + li;
        uint32_t sb = __float_as_uint(scores[i]);
        sb = (sb & 0x80000000u) ? ~sb : (sb | 0x80000000u);
        sk[li] = ((uint64_t)(~sb) << 32) | (uint32_t)i;
    }
    __syncthreads();
    for (int k = 2; k <= 2048; k <<= 1) {
        for (int j = k >> 1; j > 0; j >>= 1) {
            for (int e = 0; e < 2; ++e) {
                int li = t + e * 1024;
                int lixj = li ^ j;
                if (lixj > li) {
                    int gi = base + li;
                    bool up = ((gi & k) == 0);
                    uint64_t a = sk[li], c = sk[lixj];
                    if ((a > c) == up) { sk[li] = c; sk[lixj] = a; }
                }
            }
            __syncthreads();
        }
    }
    for (int e = 0; e < 2; ++e) { int li = t + e * 1024; keys[base + li] = sk[li]; }
}

// k=4096: cross pass j=2048 read from global (element-wise), then local j<=1024.
__global__ __launch_bounds__(1024) void k_sort2(const uint64_t* __restrict__ keys,
                                                uint64_t* __restrict__ keys2) {
    __shared__ uint64_t sk[2048];
    int b = blockIdx.x, t = threadIdx.x;
    int base = b * 2048;
    for (int e = 0; e < 2; ++e) {
        int li = t + e * 1024;
        int i = base + li;
        uint64_t a = keys[i], c = keys[i ^ 2048];
        bool up = ((i & 4096) == 0);
        bool lowpos = ((i & 2048) == 0);
        uint64_t mn = a < c ? a : c, mx = a < c ? c : a;
        sk[li] = (up == lowpos) ? mn : mx;
    }
    __syncthreads();
    for (int j = 1024; j > 0; j >>= 1) {
        for (int e = 0; e < 2; ++e) {
            int li = t + e * 1024;
            int lixj = li ^ j;
            if (lixj > li) {
                int gi = base + li;
                bool up = ((gi & 4096) == 0);
                uint64_t a = sk[li], c = sk[lixj];
                if ((a > c) == up) { sk[li] = c; sk[lixj] = a; }
            }
        }
        __syncthreads();
    }
    for (int e = 0; e < 2; ++e) { int li = t + e * 1024; keys2[base + li] = sk[li]; }
}

// k=8192 (up=true everywhere): cross passes j=4096,2048 from global, local
// j<=1024, then fused gather of boxes/scores into sorted order.
__global__ __launch_bounds__(1024) void k_sort3(const uint64_t* __restrict__ keys2,
                                                const float4* __restrict__ boxes,
                                                const float* __restrict__ scores,
                                                float4* __restrict__ bs,
                                                float* __restrict__ ss) {
    __shared__ uint64_t sk[2048];
    int b = blockIdx.x, t = threadIdx.x;
    int base = b * 2048;
    for (int e = 0; e < 2; ++e) {
        int li = t + e * 1024;
        int i = base + li;
        uint64_t a0 = keys2[i], a1 = keys2[i ^ 4096];
        bool low0 = ((i & 4096) == 0);
        uint64_t v = low0 ? (a0 < a1 ? a0 : a1) : (a0 < a1 ? a1 : a0);
        int q = i ^ 2048;
        uint64_t b0 = keys2[q], b1 = keys2[q ^ 4096];
        bool lowq = ((q & 4096) == 0);
        uint64_t vq = lowq ? (b0 < b1 ? b0 : b1) : (b0 < b1 ? b1 : b0);
        bool low2 = ((i & 2048) == 0);
        sk[li] = low2 ? (v < vq ? v : vq) : (v < vq ? vq : v);
    }
    __syncthreads();
    for (int j = 1024; j > 0; j >>= 1) {
        for (int e = 0; e < 2; ++e) {
            int li = t + e * 1024;
            int lixj = li ^ j;
            if (lixj > li) {
                uint64_t a = sk[li], c = sk[lixj];
                if (a > c) { sk[li] = c; sk[lixj] = a; }   // up = true
            }
        }
        __syncthreads();
    }
    for (int e = 0; e < 2; ++e) {
        int li = t + e * 1024;
        int gi = base + li;
        uint32_t idx = (uint32_t)sk[li];
        bs[gi] = boxes[idx];
        ss[gi] = scores[idx];
    }
}

// ---------------- Suppression bitmask + sparse packing ----------------
// Upper triangle only. Per row: diag[row] = intra-chunk word; nonzero
// off-diagonal words appended (atomicAdd cnt) to transposed pkT[e*N+row]
// (first CAP entries); dense mask kept as exact-fallback for cnt>CAP.
__global__ __launch_bounds__(256) void k_mask(const float4* __restrict__ bs,
                                              uint64_t* __restrict__ mask,
                                              ulonglong2* __restrict__ pkT,
                                              uint32_t* __restrict__ cnt,
                                              uint64_t* __restrict__ diag) {
    __shared__ float4 rb[64];
    __shared__ float  ra[64];
    int R = blockIdx.x & 127;   // row block == chunk index
    int C = blockIdx.x >> 7;    // col quarter (0..3)
    if (32 * C + 31 < R) return;   // entire block below diagonal: never read
    int t = threadIdx.x;
    int lane = t & 63;
    int wv = t >> 6;
    if (t < 64) {
        float4 b = bs[R * 64 + t];
        rb[t] = b;
        ra[t] = ((b.z - b.x) + 1.0f) * ((b.w - b.y) + 1.0f);
    }
    __syncthreads();
    for (int c = 0; c < 8; ++c) {
        int word = C * 32 + wv * 8 + c;
        if (word < R) continue;     // sub-diagonal word: never read
        int col = word * 64 + lane;
        float4 cb = bs[col];
        float ca = ((cb.z - cb.x) + 1.0f) * ((cb.w - cb.y) + 1.0f);
        for (int r = 0; r < 64; ++r) {
            int row = R * 64 + r;
            float4 rbv = rb[r];
            float ix1 = fmaxf(rbv.x, cb.x);
            float iy1 = fmaxf(rbv.y, cb.y);
            float ix2 = fminf(rbv.z, cb.z);
            float iy2 = fminf(rbv.w, cb.w);
            float iw = fmaxf((ix2 - ix1) + 1.0f, 0.0f);
            float ih = fmaxf((iy2 - iy1) + 1.0f, 0.0f);
            float inter = iw * ih;
            float uni = (ra[r] + ca) - inter;   // matches ref order
            float iou = inter / uni;            // IEEE div, matches numpy ref
            bool pred = (iou > 0.5f) && (col > row);
            uint64_t bal = __ballot(pred);
            if (lane == 0) {
                if (word == R) {
                    diag[row] = bal;                       // intra-chunk word
                } else {
                    mask[(size_t)row * 128 + word] = bal;  // dense (fallback)
                    if (bal) {
                        uint32_t pos = atomicAdd(&cnt[row], 1u);
                        if (pos < CAP) {
                            ulonglong2 v;
                            v.x = bal; v.y = (unsigned long long)word;
                            pkT[(size_t)pos * N + row] = v;
                        }
                    }
                }
            }
        }
    }
}

// ---------------- Sparse single-wave greedy scan ----------------
// 64 threads, zero barriers. Lane = row-in-chunk. Per chunk: diag/cnt
// prefetched 2 ahead, packed entries 1 ahead; ballot -> sparse scalar
// recurrence; kept lanes scatter their entries into LDS remv via atomicOr.
// cnt>CAP rows fall back to the dense mask row (exact, ~never taken).
__global__ __launch_bounds__(64) void k_scan(const uint64_t* __restrict__ mask,
                                             const ulonglong2* __restrict__ pkT,
                                             const uint32_t* __restrict__ cnt,
                                             const uint64_t* __restrict__ diag,
                                             uint64_t* __restrict__ keepw) {
    __shared__ uint64_t sh_remv[128];
    const int lane = threadIdx.x;
    sh_remv[lane] = 0;
    sh_remv[64 + lane] = 0;

    ulonglong2 PA[CAP], PB[CAP];
    uint64_t dA, dB;
    uint32_t cA, cB;
    dA = diag[lane];            cA = cnt[lane];
    dB = diag[64 + lane];       cB = cnt[64 + lane];
#pragma unroll
    for (int e = 0; e < CAP; ++e) PA[e] = pkT[(size_t)e * N + lane];

#define PROCESS(C_, CP, NP, CD, CC)                                            \
    {                                                                          \
        const int c_ = (C_);                                                   \
        uint64_t d_cur = CD;                                                   \
        uint32_t c_cur = CC;                                                   \
        if (c_ + 2 < 128) {  /* depth-2 refill of diag/cnt into own slot */    \
            int nb2 = (c_ + 2) * 64 + lane;                                    \
            CD = diag[nb2];                                                    \
            CC = cnt[nb2];                                                     \
        }                                                                      \
        if (c_ + 1 < 128) {  /* depth-1 packed-entry prefetch */               \
            int nb = (c_ + 1) * 64 + lane;                                     \
            _Pragma("unroll")                                                  \
            for (int e = 0; e < CAP; ++e) NP[e] = pkT[(size_t)e * N + nb];     \
        }                                                                      \
        uint64_t nzv = __ballot(d_cur != 0);                                   \
        uint32_t nlo = __builtin_amdgcn_readfirstlane((uint32_t)nzv);          \
        uint32_t nhi = __builtin_amdgcn_readfirstlane((uint32_t)(nzv >> 32));  \
        uint64_t nz = ((uint64_t)nhi << 32) | nlo;                             \
        uint32_t mlo = (uint32_t)d_cur, mhi = (uint32_t)(d_cur >> 32);         \
        asm volatile("s_waitcnt lgkmcnt(0)" ::: "memory");                     \
        uint64_t wvv = sh_remv[c_];                                            \
        uint32_t wlo = __builtin_amdgcn_readfirstlane((uint32_t)wvv);          \
        uint32_t whi = __builtin_amdgcn_readfirstlane((uint32_t)(wvv >> 32));  \
        uint64_t w_ = ((uint64_t)whi << 32) | wlo;                             \
        while (nz) {  /* sparse serial recurrence over nonzero-diag rows */    \
            int i = (int)__builtin_ctzll(nz);                                  \
            nz &= nz - 1;                                                      \
            if (!((w_ >> i) & 1ull)) {                                         \
                uint32_t lo = __builtin_amdgcn_readlane(mlo, i);               \
                uint32_t hi = __builtin_amdgcn_readlane(mhi, i);               \
                w_ |= ((uint64_t)hi << 32) | lo;                               \
            }                                                                  \
        }                                                                      \
        if (lane == 0) keepw[c_] = ~w_;                                        \
        if (!((w_ >> lane) & 1ull)) {  /* kept: scatter future words */        \
            if (c_cur <= CAP) {                                                \
                _Pragma("unroll")                                              \
                for (int e = 0; e < CAP; ++e) {                                \
                    if (e < (int)c_cur) {                                      \
                        atomicOr((unsigned long long*)&sh_remv[(int)CP[e].y],  \
                                 (unsigned long long)CP[e].x);                 \
                    }                                                          \
                }                                                              \
            } else {  /* exact fallback: dense row (essentially never) */      \
                int row = c_ * 64 + lane;                                      \
                for (int w = c_ + 1; w < 128; ++w) {                           \
                    uint64_t v = mask[(size_t)row * 128 + w];                  \
                    if (v) atomicOr((unsigned long long*)&sh_remv[w],          \
                                    (unsigned long long)v);                    \
                }                                                              \
            }                                                                  \
        }                                                                      \
    }

    for (int cc = 0; cc < 128; cc += 2) {
        PROCESS(cc, PA, PB, dA, cA)
        PROCESS(cc + 1, PB, PA, dB, cB)
    }
#undef PROCESS
}

// ---------------- Masked outputs ----------------
__global__ void k_out(const float4* __restrict__ bs, const float* __restrict__ ss,
                      const uint64_t* __restrict__ keepw, float* __restrict__ out) {
    int i = blockIdx.x * blockDim.x + threadIdx.x;
    uint64_t wv = keepw[i >> 6];
    float m = ((wv >> (i & 63)) & 1ull) ? 1.0f : 0.0f;
    float4 b = bs[i];
    float4 ob;
    ob.x = b.x * m; ob.y = b.y * m; ob.z = b.z * m; ob.w = b.w * m;
    ((float4*)out)[i] = ob;
    out[4 * N + i] = ss[i] * m;
    out[5 * N + i] = m;
}

extern "C" void kernel_launch(void* const* d_in, const int* in_sizes, int n_in,
                              void* d_out, int out_size, void* d_ws, size_t ws_size,
                              hipStream_t stream) {
    const float* boxes  = (const float*)d_in[0];   // 8192 x 4 f32
    const float* scores = (const float*)d_in[1];   // 8192 f32

    char* ws = (char*)d_ws;
    float4*     bs    = (float4*)(ws + 0);           // 131072 B
    float*      ss    = (float*)(ws + 131072);       //  32768 B
    uint64_t*   keepw = (uint64_t*)(ws + 163840);    //   1024 B
    uint64_t*   mask  = (uint64_t*)(ws + 262144);    // 8388608 B (8192 x 128 u64)
    // keys/keys2 overlap mask: sort finishes before k_mask writes it.
    uint64_t*   keys  = (uint64_t*)(ws + 262144);
    uint64_t*   keys2 = (uint64_t*)(ws + 262144 + 65536);
    ulonglong2* pkT   = (ulonglong2*)(ws + 8650752); // 2097152 B (CAP x 8192 x 16)
    uint32_t*   cnt   = (uint32_t*)(ws + 10747904);  //   32768 B
    uint64_t*   diag  = (uint64_t*)(ws + 10780672);  //   65536 B

    k_sort1<<<4, 1024, 0, stream>>>(scores, keys, cnt);
    k_sort2<<<4, 1024, 0, stream>>>(keys, keys2);
    k_sort3<<<4, 1024, 0, stream>>>(keys2, (const float4*)boxes, scores, bs, ss);
    k_mask <<<512, 256, 0, stream>>>(bs, mask, pkT, cnt, diag);
    k_scan <<<1, 64, 0, stream>>>(mask, pkT, cnt, diag, keepw);
    k_out  <<<N / 256, 256, 0, stream>>>(bs, ss, keepw, (float*)d_out);
}

// Round 7
// 170.351 us; speedup vs baseline: 16.4954x; 1.4604x over previous
//
#include <hip/hip_runtime.h>
#include <stdint.h>
#include <math.h>

#define N 8192
#define CAP 16
#define OVF_MAX 1024

// ================= Sort stage (bitonic, exact argsort) =================
// key = (~monotone(score) << 32) | index; ascending sort == stable argsort
// of -scores. Network split: local k<=2048 (s1), k=4096 (s2), k=8192 (s3).

__global__ __launch_bounds__(1024) void k_sort1(const float* __restrict__ scores,
                                                uint64_t* __restrict__ keys,
                                                uint32_t* __restrict__ cnt,
                                                uint32_t* __restrict__ ovfc) {
    __shared__ uint64_t sk[2048];
    int b = blockIdx.x, t = threadIdx.x;
    int base = b * 2048;
    // zero the per-row packed-entry counters (must happen before k_mask).
    cnt[base + t] = 0;
    cnt[base + t + 1024] = 0;
    if (b == 0 && t == 0) *ovfc = 0;
    for (int e = 0; e < 2; ++e) {
        int li = t + e * 1024;
        int i = base + li;
        uint32_t sb = __float_as_uint(scores[i]);
        sb = (sb & 0x80000000u) ? ~sb : (sb | 0x80000000u);
        sk[li] = ((uint64_t)(~sb) << 32) | (uint32_t)i;
    }
    __syncthreads();
    for (int k = 2; k <= 2048; k <<= 1) {
        for (int j = k >> 1; j > 0; j >>= 1) {
            for (int e = 0; e < 2; ++e) {
                int li = t + e * 1024;
                int lixj = li ^ j;
                if (lixj > li) {
                    int gi = base + li;
                    bool up = ((gi & k) == 0);
                    uint64_t a = sk[li], c = sk[lixj];
                    if ((a > c) == up) { sk[li] = c; sk[lixj] = a; }
                }
            }
            __syncthreads();
        }
    }
    for (int e = 0; e < 2; ++e) { int li = t + e * 1024; keys[base + li] = sk[li]; }
}

// k=4096: cross pass j=2048 read from global (element-wise), then local j<=1024.
__global__ __launch_bounds__(1024) void k_sort2(const uint64_t* __restrict__ keys,
                                                uint64_t* __restrict__ keys2) {
    __shared__ uint64_t sk[2048];
    int b = blockIdx.x, t = threadIdx.x;
    int base = b * 2048;
    for (int e = 0; e < 2; ++e) {
        int li = t + e * 1024;
        int i = base + li;
        uint64_t a = keys[i], c = keys[i ^ 2048];
        bool up = ((i & 4096) == 0);
        bool lowpos = ((i & 2048) == 0);
        uint64_t mn = a < c ? a : c, mx = a < c ? c : a;
        sk[li] = (up == lowpos) ? mn : mx;
    }
    __syncthreads();
    for (int j = 1024; j > 0; j >>= 1) {
        for (int e = 0; e < 2; ++e) {
            int li = t + e * 1024;
            int lixj = li ^ j;
            if (lixj > li) {
                int gi = base + li;
                bool up = ((gi & 4096) == 0);
                uint64_t a = sk[li], c = sk[lixj];
                if ((a > c) == up) { sk[li] = c; sk[lixj] = a; }
            }
        }
        __syncthreads();
    }
    for (int e = 0; e < 2; ++e) { int li = t + e * 1024; keys2[base + li] = sk[li]; }
}

// k=8192 (up=true everywhere): cross passes j=4096,2048 from global, local
// j<=1024, then fused gather of boxes/scores into sorted order.
__global__ __launch_bounds__(1024) void k_sort3(const uint64_t* __restrict__ keys2,
                                                const float4* __restrict__ boxes,
                                                const float* __restrict__ scores,
                                                float4* __restrict__ bs,
                                                float* __restrict__ ss) {
    __shared__ uint64_t sk[2048];
    int b = blockIdx.x, t = threadIdx.x;
    int base = b * 2048;
    for (int e = 0; e < 2; ++e) {
        int li = t + e * 1024;
        int i = base + li;
        uint64_t a0 = keys2[i], a1 = keys2[i ^ 4096];
        bool low0 = ((i & 4096) == 0);
        uint64_t v = low0 ? (a0 < a1 ? a0 : a1) : (a0 < a1 ? a1 : a0);
        int q = i ^ 2048;
        uint64_t b0 = keys2[q], b1 = keys2[q ^ 4096];
        bool lowq = ((q & 4096) == 0);
        uint64_t vq = lowq ? (b0 < b1 ? b0 : b1) : (b0 < b1 ? b1 : b0);
        bool low2 = ((i & 2048) == 0);
        sk[li] = low2 ? (v < vq ? v : vq) : (v < vq ? vq : v);
    }
    __syncthreads();
    for (int j = 1024; j > 0; j >>= 1) {
        for (int e = 0; e < 2; ++e) {
            int li = t + e * 1024;
            int lixj = li ^ j;
            if (lixj > li) {
                uint64_t a = sk[li], c = sk[lixj];
                if (a > c) { sk[li] = c; sk[lixj] = a; }   // up = true
            }
        }
        __syncthreads();
    }
    for (int e = 0; e < 2; ++e) {
        int li = t + e * 1024;
        int gi = base + li;
        uint32_t idx = (uint32_t)sk[li];
        bs[gi] = boxes[idx];
        ss[gi] = scores[idx];
    }
}

// ---------------- Suppression bitmask -> sparse packed ----------------
// One wave per upper-triangle (R, word) tile; 8256 tiles = 2064 blocks x 4
// waves, perfectly balanced, zero barriers. Per row: diag word to diag[],
// nonzero off-diagonal words appended (atomicAdd cnt) to transposed
// pkT[e*N+row]; entries beyond CAP go to a tiny global overflow list.
__global__ __launch_bounds__(256) void k_mask(const float4* __restrict__ bs,
                                              ulonglong2* __restrict__ pkT,
                                              uint32_t* __restrict__ cnt,
                                              uint64_t* __restrict__ diag,
                                              ulonglong2* __restrict__ ovf,
                                              uint32_t* __restrict__ ovfc) {
    __shared__ float4 rb[4][64];
    __shared__ float  ra[4][64];
    int t = threadIdx.x;
    int lane = t & 63;
    int wv = t >> 6;
    int tile = blockIdx.x * 4 + wv;          // 0..8255

    // decode tile -> (R, word): off(R) = 128R - R(R-1)/2, word >= R
    int R = (int)((257.0 - sqrt(66049.0 - 8.0 * (double)tile)) * 0.5);
    while (128 * (R + 1) - ((R + 1) * R) / 2 <= tile) ++R;   // safety correction
    while (128 * R - (R * (R - 1)) / 2 > tile) --R;
    int word = R + tile - (128 * R - (R * (R - 1)) / 2);

    {   // stage this wave's 64 row boxes (wave-private LDS, no barrier needed)
        float4 b = bs[R * 64 + lane];
        rb[wv][lane] = b;
        ra[wv][lane] = ((b.z - b.x) + 1.0f) * ((b.w - b.y) + 1.0f);
    }
    int col = word * 64 + lane;
    float4 cb = bs[col];
    float ca = ((cb.z - cb.x) + 1.0f) * ((cb.w - cb.y) + 1.0f);

    for (int r = 0; r < 64; ++r) {
        int row = R * 64 + r;
        float4 rbv = rb[wv][r];
        float ix1 = fmaxf(rbv.x, cb.x);
        float iy1 = fmaxf(rbv.y, cb.y);
        float ix2 = fminf(rbv.z, cb.z);
        float iy2 = fminf(rbv.w, cb.w);
        float iw = fmaxf((ix2 - ix1) + 1.0f, 0.0f);
        float ih = fmaxf((iy2 - iy1) + 1.0f, 0.0f);
        float inter = iw * ih;
        float uni = (ra[wv][r] + ca) - inter;   // matches ref order
        float iou = inter / uni;                // IEEE div, matches numpy ref
        bool pred = (iou > 0.5f) && (col > row);
        uint64_t bal = __ballot(pred);
        if (lane == 0) {
            if (word == R) {
                diag[row] = bal;                 // intra-chunk word
            } else if (bal) {
                uint32_t pos = atomicAdd(&cnt[row], 1u);
                if (pos < CAP) {
                    ulonglong2 v;
                    v.x = bal; v.y = (unsigned long long)word;
                    pkT[(size_t)pos * N + row] = v;
                } else {
                    uint32_t op = atomicAdd(ovfc, 1u);
                    if (op < OVF_MAX) {
                        ulonglong2 v;
                        v.x = bal;
                        v.y = (unsigned long long)word |
                              ((unsigned long long)row << 32);
                        ovf[op] = v;
                    }
                }
            }
        }
    }
}

// ---------------- Sparse single-wave greedy scan ----------------
// 64 threads, zero barriers. Lane = row-in-chunk. diag/cnt prefetched 2
// chunks ahead, packed entries 1 ahead; ballot -> sparse scalar recurrence;
// kept lanes scatter their entries into LDS remv via atomicOr. Rows with
// cnt>CAP are completed exactly from the overflow list (ballot-gated).
__global__ __launch_bounds__(64) void k_scan(const ulonglong2* __restrict__ pkT,
                                             const uint32_t* __restrict__ cnt,
                                             const uint64_t* __restrict__ diag,
                                             const ulonglong2* __restrict__ ovf,
                                             const uint32_t* __restrict__ ovfc,
                                             uint64_t* __restrict__ keepw) {
    __shared__ uint64_t sh_remv[128];
    const int lane = threadIdx.x;
    sh_remv[lane] = 0;
    sh_remv[64 + lane] = 0;
    const int novf = min((int)*ovfc, OVF_MAX);

    ulonglong2 PA[CAP], PB[CAP];
    uint64_t dA, dB;
    uint32_t cA, cB;
    dA = diag[lane];            cA = cnt[lane];
    dB = diag[64 + lane];       cB = cnt[64 + lane];
#pragma unroll
    for (int e = 0; e < CAP; ++e) PA[e] = pkT[(size_t)e * N + lane];

#define PROCESS(C_, CP, NP, CD, CC)                                            \
    {                                                                          \
        const int c_ = (C_);                                                   \
        uint64_t d_cur = CD;                                                   \
        uint32_t c_cur = CC;                                                   \
        if (c_ + 2 < 128) {  /* depth-2 refill of diag/cnt into own slot */    \
            int nb2 = (c_ + 2) * 64 + lane;                                    \
            CD = diag[nb2];                                                    \
            CC = cnt[nb2];                                                     \
        }                                                                      \
        if (c_ + 1 < 128) {  /* depth-1 packed-entry prefetch */               \
            int nb = (c_ + 1) * 64 + lane;                                     \
            _Pragma("unroll")                                                  \
            for (int e = 0; e < CAP; ++e) NP[e] = pkT[(size_t)e * N + nb];     \
        }                                                                      \
        uint64_t nzv = __ballot(d_cur != 0);                                   \
        uint32_t nlo = __builtin_amdgcn_readfirstlane((uint32_t)nzv);          \
        uint32_t nhi = __builtin_amdgcn_readfirstlane((uint32_t)(nzv >> 32));  \
        uint64_t nz = ((uint64_t)nhi << 32) | nlo;                             \
        uint32_t mlo = (uint32_t)d_cur, mhi = (uint32_t)(d_cur >> 32);         \
        asm volatile("s_waitcnt lgkmcnt(0)" ::: "memory");                     \
        uint64_t wvv = sh_remv[c_];                                            \
        uint32_t wlo = __builtin_amdgcn_readfirstlane((uint32_t)wvv);          \
        uint32_t whi = __builtin_amdgcn_readfirstlane((uint32_t)(wvv >> 32));  \
        uint64_t w_ = ((uint64_t)whi << 32) | wlo;                             \
        while (nz) {  /* sparse serial recurrence over nonzero-diag rows */    \
            int i = (int)__builtin_ctzll(nz);                                  \
            nz &= nz - 1;                                                      \
            if (!((w_ >> i) & 1ull)) {                                         \
                uint32_t lo = __builtin_amdgcn_readlane(mlo, i);               \
                uint32_t hi = __builtin_amdgcn_readlane(mhi, i);               \
                w_ |= ((uint64_t)hi << 32) | lo;                               \
            }                                                                  \
        }                                                                      \
        if (lane == 0) keepw[c_] = ~w_;                                        \
        if (!((w_ >> lane) & 1ull)) {  /* kept: scatter future words */        \
            _Pragma("unroll")                                                  \
            for (int e = 0; e < CAP; ++e) {                                    \
                if (e < (int)c_cur) {                                          \
                    atomicOr((unsigned long long*)&sh_remv[(int)CP[e].y],      \
                             (unsigned long long)CP[e].x);                     \
                }                                                              \
            }                                                                  \
        }                                                                      \
        uint64_t ovb = __ballot(c_cur > CAP);  /* exact overflow completion */ \
        if (ovb) {                                                             \
            for (int e = lane; e < novf; e += 64) {                            \
                ulonglong2 en = ovf[e];                                        \
                int erow = (int)(en.y >> 32);                                  \
                if ((erow >> 6) == c_ && !((w_ >> (erow & 63)) & 1ull))        \
                    atomicOr((unsigned long long*)&sh_remv[(int)(uint32_t)en.y],\
                             (unsigned long long)en.x);                        \
            }                                                                  \
        }                                                                      \
    }

    for (int cc = 0; cc < 128; cc += 2) {
        PROCESS(cc, PA, PB, dA, cA)
        PROCESS(cc + 1, PB, PA, dB, cB)
    }
#undef PROCESS
}

// ---------------- Masked outputs ----------------
__global__ void k_out(const float4* __restrict__ bs, const float* __restrict__ ss,
                      const uint64_t* __restrict__ keepw, float* __restrict__ out) {
    int i = blockIdx.x * blockDim.x + threadIdx.x;
    uint64_t wv = keepw[i >> 6];
    float m = ((wv >> (i & 63)) & 1ull) ? 1.0f : 0.0f;
    float4 b = bs[i];
    float4 ob;
    ob.x = b.x * m; ob.y = b.y * m; ob.z = b.z * m; ob.w = b.w * m;
    ((float4*)out)[i] = ob;
    out[4 * N + i] = ss[i] * m;
    out[5 * N + i] = m;
}

extern "C" void kernel_launch(void* const* d_in, const int* in_sizes, int n_in,
                              void* d_out, int out_size, void* d_ws, size_t ws_size,
                              hipStream_t stream) {
    const float* boxes  = (const float*)d_in[0];   // 8192 x 4 f32
    const float* scores = (const float*)d_in[1];   // 8192 f32

    char* ws = (char*)d_ws;
    float4*     bs    = (float4*)(ws + 0);          // 131072 B
    float*      ss    = (float*)(ws + 131072);      //  32768 B
    uint64_t*   keepw = (uint64_t*)(ws + 163840);   //   1024 B
    uint32_t*   cnt   = (uint32_t*)(ws + 164864);   //  32768 B
    uint64_t*   diag  = (uint64_t*)(ws + 197632);   //  65536 B
    uint32_t*   ovfc  = (uint32_t*)(ws + 263168);   //      4 B (padded)
    ulonglong2* ovf   = (ulonglong2*)(ws + 263680); //  16384 B (1024 x 16)
    uint64_t*   keys  = (uint64_t*)(ws + 280064);   //  65536 B
    uint64_t*   keys2 = (uint64_t*)(ws + 345600);   //  65536 B
    ulonglong2* pkT   = (ulonglong2*)(ws + 524288); // 2097152 B (CAP x N x 16)

    k_sort1<<<4, 1024, 0, stream>>>(scores, keys, cnt, ovfc);
    k_sort2<<<4, 1024, 0, stream>>>(keys, keys2);
    k_sort3<<<4, 1024, 0, stream>>>(keys2, (const float4*)boxes, scores, bs, ss);
    k_mask <<<2064, 256, 0, stream>>>(bs, pkT, cnt, diag, ovf, ovfc);
    k_scan <<<1, 64, 0, stream>>>(pkT, cnt, diag, ovf, ovfc, keepw);
    k_out  <<<N / 256, 256, 0, stream>>>(bs, ss, keepw, (float*)d_out);
}

// Round 9
// 152.816 us; speedup vs baseline: 18.3881x; 1.1147x over previous
//
#include <hip/hip_runtime.h>
#include <stdint.h>
#include <math.h>

#define N 8192
#define CAP 8
#define OVF_MAX 4096

// ================= Sort stage (bitonic, exact argsort) =================
// key = (~monotone(score) << 32) | index; ascending sort == stable argsort
// of -scores. Network split: local k<=2048 (s1), k=4096 (s2), k=8192 (s3).

__global__ __launch_bounds__(1024) void k_sort1(const float* __restrict__ scores,
                                                uint64_t* __restrict__ keys,
                                                uint32_t* __restrict__ cnt,
                                                uint32_t* __restrict__ ovfc) {
    __shared__ uint64_t sk[2048];
    int b = blockIdx.x, t = threadIdx.x;
    int base = b * 2048;
    // zero the per-row packed-entry counters (must happen before k_mask).
    cnt[base + t] = 0;
    cnt[base + t + 1024] = 0;
    if (b == 0 && t == 0) *ovfc = 0;
    for (int e = 0; e < 2; ++e) {
        int li = t + e * 1024;
        int i = base + li;
        uint32_t sb = __float_as_uint(scores[i]);
        sb = (sb & 0x80000000u) ? ~sb : (sb | 0x80000000u);
        sk[li] = ((uint64_t)(~sb) << 32) | (uint32_t)i;
    }
    __syncthreads();
    for (int k = 2; k <= 2048; k <<= 1) {
        for (int j = k >> 1; j > 0; j >>= 1) {
            for (int e = 0; e < 2; ++e) {
                int li = t + e * 1024;
                int lixj = li ^ j;
                if (lixj > li) {
                    int gi = base + li;
                    bool up = ((gi & k) == 0);
                    uint64_t a = sk[li], c = sk[lixj];
                    if ((a > c) == up) { sk[li] = c; sk[lixj] = a; }
                }
            }
            __syncthreads();
        }
    }
    for (int e = 0; e < 2; ++e) { int li = t + e * 1024; keys[base + li] = sk[li]; }
}

// k=4096: cross pass j=2048 read from global (element-wise), then local j<=1024.
__global__ __launch_bounds__(1024) void k_sort2(const uint64_t* __restrict__ keys,
                                                uint64_t* __restrict__ keys2) {
    __shared__ uint64_t sk[2048];
    int b = blockIdx.x, t = threadIdx.x;
    int base = b * 2048;
    for (int e = 0; e < 2; ++e) {
        int li = t + e * 1024;
        int i = base + li;
        uint64_t a = keys[i], c = keys[i ^ 2048];
        bool up = ((i & 4096) == 0);
        bool lowpos = ((i & 2048) == 0);
        uint64_t mn = a < c ? a : c, mx = a < c ? c : a;
        sk[li] = (up == lowpos) ? mn : mx;
    }
    __syncthreads();
    for (int j = 1024; j > 0; j >>= 1) {
        for (int e = 0; e < 2; ++e) {
            int li = t + e * 1024;
            int lixj = li ^ j;
            if (lixj > li) {
                int gi = base + li;
                bool up = ((gi & 4096) == 0);
                uint64_t a = sk[li], c = sk[lixj];
                if ((a > c) == up) { sk[li] = c; sk[lixj] = a; }
            }
        }
        __syncthreads();
    }
    for (int e = 0; e < 2; ++e) { int li = t + e * 1024; keys2[base + li] = sk[li]; }
}

// k=8192 (up=true everywhere): cross passes j=4096,2048 from global, local
// j<=1024, then fused gather of boxes/scores into sorted order.
__global__ __launch_bounds__(1024) void k_sort3(const uint64_t* __restrict__ keys2,
                                                const float4* __restrict__ boxes,
                                                const float* __restrict__ scores,
                                                float4* __restrict__ bs,
                                                float* __restrict__ ss) {
    __shared__ uint64_t sk[2048];
    int b = blockIdx.x, t = threadIdx.x;
    int base = b * 2048;
    for (int e = 0; e < 2; ++e) {
        int li = t + e * 1024;
        int i = base + li;
        uint64_t a0 = keys2[i], a1 = keys2[i ^ 4096];
        bool low0 = ((i & 4096) == 0);
        uint64_t v = low0 ? (a0 < a1 ? a0 : a1) : (a0 < a1 ? a1 : a0);
        int q = i ^ 2048;
        uint64_t b0 = keys2[q], b1 = keys2[q ^ 4096];
        bool lowq = ((q & 4096) == 0);
        uint64_t vq = lowq ? (b0 < b1 ? b0 : b1) : (b0 < b1 ? b1 : b0);
        bool low2 = ((i & 2048) == 0);
        sk[li] = low2 ? (v < vq ? v : vq) : (v < vq ? vq : v);
    }
    __syncthreads();
    for (int j = 1024; j > 0; j >>= 1) {
        for (int e = 0; e < 2; ++e) {
            int li = t + e * 1024;
            int lixj = li ^ j;
            if (lixj > li) {
                uint64_t a = sk[li], c = sk[lixj];
                if (a > c) { sk[li] = c; sk[lixj] = a; }   // up = true
            }
        }
        __syncthreads();
    }
    for (int e = 0; e < 2; ++e) {
        int li = t + e * 1024;
        int gi = base + li;
        uint32_t idx = (uint32_t)sk[li];
        bs[gi] = boxes[idx];
        ss[gi] = scores[idx];
    }
}

// ---------------- Suppression bitmask -> sparse packed ----------------
// One wave per upper-triangle (R, word) tile; 8256 tiles = 2064 blocks x 4
// waves, perfectly balanced, zero barriers. Per row: diag word to diag[],
// nonzero off-diagonal words appended (atomicAdd cnt) to transposed
// pkT[e*N+row]; entries beyond CAP go to a tiny global overflow list.
__global__ __launch_bounds__(256) void k_mask(const float4* __restrict__ bs,
                                              ulonglong2* __restrict__ pkT,
                                              uint32_t* __restrict__ cnt,
                                              uint64_t* __restrict__ diag,
                                              ulonglong2* __restrict__ ovf,
                                              uint32_t* __restrict__ ovfc) {
    __shared__ float4 rb[4][64];
    __shared__ float  ra[4][64];
    int t = threadIdx.x;
    int lane = t & 63;
    int wv = t >> 6;
    int tile = blockIdx.x * 4 + wv;          // 0..8255

    // decode tile -> (R, word): off(R) = 128R - R(R-1)/2, word >= R
    int R = (int)((257.0 - sqrt(66049.0 - 8.0 * (double)tile)) * 0.5);
    while (128 * (R + 1) - ((R + 1) * R) / 2 <= tile) ++R;   // safety correction
    while (128 * R - (R * (R - 1)) / 2 > tile) --R;
    int word = R + tile - (128 * R - (R * (R - 1)) / 2);

    {   // stage this wave's 64 row boxes (wave-private LDS, no barrier needed)
        float4 b = bs[R * 64 + lane];
        rb[wv][lane] = b;
        ra[wv][lane] = ((b.z - b.x) + 1.0f) * ((b.w - b.y) + 1.0f);
    }
    int col = word * 64 + lane;
    float4 cb = bs[col];
    float ca = ((cb.z - cb.x) + 1.0f) * ((cb.w - cb.y) + 1.0f);

    for (int r = 0; r < 64; ++r) {
        int row = R * 64 + r;
        float4 rbv = rb[wv][r];
        float ix1 = fmaxf(rbv.x, cb.x);
        float iy1 = fmaxf(rbv.y, cb.y);
        float ix2 = fminf(rbv.z, cb.z);
        float iy2 = fminf(rbv.w, cb.w);
        float iw = fmaxf((ix2 - ix1) + 1.0f, 0.0f);
        float ih = fmaxf((iy2 - iy1) + 1.0f, 0.0f);
        float inter = iw * ih;
        float uni = (ra[wv][r] + ca) - inter;   // matches ref order
        float iou = inter / uni;                // IEEE div, matches numpy ref
        bool pred = (iou > 0.5f) && (col > row);
        uint64_t bal = __ballot(pred);
        if (lane == 0) {
            if (word == R) {
                diag[row] = bal;                 // intra-chunk word
            } else if (bal) {
                uint32_t pos = atomicAdd(&cnt[row], 1u);
                if (pos < CAP) {
                    ulonglong2 v;
                    v.x = bal; v.y = (unsigned long long)word;
                    pkT[(size_t)pos * N + row] = v;
                } else {
                    uint32_t op = atomicAdd(ovfc, 1u);
                    if (op < OVF_MAX) {
                        ulonglong2 v;
                        v.x = bal;
                        v.y = (unsigned long long)word |
                              ((unsigned long long)row << 32);
                        ovf[op] = v;
                    }
                }
            }
        }
    }
}

// ---------------- Sparse single-wave greedy scan ----------------
// 64 threads, zero barriers. Lane = row-in-chunk. diag/cnt prefetched 2
// chunks ahead, packed entries 1 ahead; ballot -> sparse scalar recurrence;
// kept lanes scatter their entries into LDS remv via atomicOr. Rows with
// cnt>CAP are completed exactly from the overflow list (ballot-gated).
// CAP=8 keeps PA+PB at 64 VGPRs so the prefetch buffers stay register-
// resident (CAP=16 spilled: VGPR_Count=80 < 128 needed -> de-pipelined).
__global__ __launch_bounds__(64, 1) void k_scan(const ulonglong2* __restrict__ pkT,
                                                const uint32_t* __restrict__ cnt,
                                                const uint64_t* __restrict__ diag,
                                                const ulonglong2* __restrict__ ovf,
                                                const uint32_t* __restrict__ ovfc,
                                                uint64_t* __restrict__ keepw) {
    __shared__ uint64_t sh_remv[128];
    const int lane = threadIdx.x;
    sh_remv[lane] = 0;
    sh_remv[64 + lane] = 0;
    const int novf = min((int)*ovfc, OVF_MAX);

    ulonglong2 PA[CAP], PB[CAP];
    uint64_t dA, dB;
    uint32_t cA, cB;
    dA = diag[lane];            cA = cnt[lane];
    dB = diag[64 + lane];       cB = cnt[64 + lane];
#pragma unroll
    for (int e = 0; e < CAP; ++e) PA[e] = pkT[(size_t)e * N + lane];

#define PROCESS(C_, CP, NP, CD, CC)                                            \
    {                                                                          \
        const int c_ = (C_);                                                   \
        uint64_t d_cur = CD;                                                   \
        uint32_t c_cur = CC;                                                   \
        if (c_ + 2 < 128) {  /* depth-2 refill of diag/cnt into own slot */    \
            int nb2 = (c_ + 2) * 64 + lane;                                    \
            CD = diag[nb2];                                                    \
            CC = cnt[nb2];                                                     \
        }                                                                      \
        if (c_ + 1 < 128) {  /* depth-1 packed-entry prefetch */               \
            int nb = (c_ + 1) * 64 + lane;                                     \
            _Pragma("unroll")                                                  \
            for (int e = 0; e < CAP; ++e) NP[e] = pkT[(size_t)e * N + nb];     \
        }                                                                      \
        uint64_t nzv = __ballot(d_cur != 0);                                   \
        uint32_t nlo = __builtin_amdgcn_readfirstlane((uint32_t)nzv);          \
        uint32_t nhi = __builtin_amdgcn_readfirstlane((uint32_t)(nzv >> 32));  \
        uint64_t nz = ((uint64_t)nhi << 32) | nlo;                             \
        uint32_t mlo = (uint32_t)d_cur, mhi = (uint32_t)(d_cur >> 32);         \
        asm volatile("s_waitcnt lgkmcnt(0)" ::: "memory");                     \
        uint64_t wvv = sh_remv[c_];                                            \
        uint32_t wlo = __builtin_amdgcn_readfirstlane((uint32_t)wvv);          \
        uint32_t whi = __builtin_amdgcn_readfirstlane((uint32_t)(wvv >> 32));  \
        uint64_t w_ = ((uint64_t)whi << 32) | wlo;                             \
        while (nz) {  /* sparse serial recurrence over nonzero-diag rows */    \
            int i = (int)__builtin_ctzll(nz);                                  \
            nz &= nz - 1;                                                      \
            if (!((w_ >> i) & 1ull)) {                                         \
                uint32_t lo = __builtin_amdgcn_readlane(mlo, i);               \
                uint32_t hi = __builtin_amdgcn_readlane(mhi, i);               \
                w_ |= ((uint64_t)hi << 32) | lo;                               \
            }                                                                  \
        }                                                                      \
        if (lane == 0) keepw[c_] = ~w_;                                        \
        if (!((w_ >> lane) & 1ull)) {  /* kept: scatter future words */        \
            _Pragma("unroll")                                                  \
            for (int e = 0; e < CAP; ++e) {                                    \
                if (e < (int)c_cur) {                                          \
                    atomicOr((unsigned long long*)&sh_remv[(int)CP[e].y],      \
                             (unsigned long long)CP[e].x);                     \
                }                                                              \
            }                                                                  \
        }                                                                      \
        uint64_t ovb = __ballot(c_cur > CAP);  /* exact overflow completion */ \
        if (ovb) {                                                             \
            for (int e = lane; e < novf; e += 64) {                            \
                ulonglong2 en = ovf[e];                                        \
                int erow = (int)(en.y >> 32);                                  \
                if ((erow >> 6) == c_ && !((w_ >> (erow & 63)) & 1ull))        \
                    atomicOr((unsigned long long*)&sh_remv[(int)(uint32_t)en.y],\
                             (unsigned long long)en.x);                        \
            }                                                                  \
        }                                                                      \
    }

    for (int cc = 0; cc < 128; cc += 2) {
        PROCESS(cc, PA, PB, dA, cA)
        PROCESS(cc + 1, PB, PA, dB, cB)
    }
#undef PROCESS
}

// ---------------- Masked outputs ----------------
__global__ void k_out(const float4* __restrict__ bs, const float* __restrict__ ss,
                      const uint64_t* __restrict__ keepw, float* __restrict__ out) {
    int i = blockIdx.x * blockDim.x + threadIdx.x;
    uint64_t wv = keepw[i >> 6];
    float m = ((wv >> (i & 63)) & 1ull) ? 1.0f : 0.0f;
    float4 b = bs[i];
    float4 ob;
    ob.x = b.x * m; ob.y = b.y * m; ob.z = b.z * m; ob.w = b.w * m;
    ((float4*)out)[i] = ob;
    out[4 * N + i] = ss[i] * m;
    out[5 * N + i] = m;
}

extern "C" void kernel_launch(void* const* d_in, const int* in_sizes, int n_in,
                              void* d_out, int out_size, void* d_ws, size_t ws_size,
                              hipStream_t stream) {
    const float* boxes  = (const float*)d_in[0];   // 8192 x 4 f32
    const float* scores = (const float*)d_in[1];   // 8192 f32

    char* ws = (char*)d_ws;
    float4*     bs    = (float4*)(ws + 0);          // 131072 B
    float*      ss    = (float*)(ws + 131072);      //  32768 B
    uint64_t*   keepw = (uint64_t*)(ws + 163840);   //   1024 B
    uint32_t*   cnt   = (uint32_t*)(ws + 164864);   //  32768 B
    uint64_t*   diag  = (uint64_t*)(ws + 197632);   //  65536 B
    uint32_t*   ovfc  = (uint32_t*)(ws + 263168);   //      4 B (padded)
    ulonglong2* ovf   = (ulonglong2*)(ws + 263680); //  65536 B (4096 x 16)
    uint64_t*   keys  = (uint64_t*)(ws + 329216);   //  65536 B
    uint64_t*   keys2 = (uint64_t*)(ws + 394752);   //  65536 B
    ulonglong2* pkT   = (ulonglong2*)(ws + 524288); // 1048576 B (CAP x N x 16)

    k_sort1<<<4, 1024, 0, stream>>>(scores, keys, cnt, ovfc);
    k_sort2<<<4, 1024, 0, stream>>>(keys, keys2);
    k_sort3<<<4, 1024, 0, stream>>>(keys2, (const float4*)boxes, scores, bs, ss);
    k_mask <<<2064, 256, 0, stream>>>(bs, pkT, cnt, diag, ovf, ovfc);
    k_scan <<<1, 64, 0, stream>>>(pkT, cnt, diag, ovf, ovfc, keepw);
    k_out  <<<N / 256, 256, 0, stream>>>(bs, ss, keepw, (float*)d_out);
}